// Round 1
// baseline (396.943 us; speedup 1.0000x reference)
//
#include <hip/hip_runtime.h>
#include <cstdint>
#include <cstddef>

typedef unsigned short u16;
typedef __attribute__((ext_vector_type(8))) short s16x8;
typedef __attribute__((ext_vector_type(4))) float f32x4;

#define DEV __device__ __forceinline__

DEV float bf2f(short u){
  union { unsigned int i; float f; } v;
  v.i = ((unsigned int)(u16)u) << 16;
  return v.f;
}
DEV short f2bf(float f){
  union { float f; unsigned int i; } v; v.f = f;
  unsigned int u = v.i;
  u += 0x7fffu + ((u >> 16) & 1u);   // RNE
  return (short)(u >> 16);
}
DEV s16x8 s16x8_zero(){
  s16x8 z;
#pragma unroll
  for(int j=0;j<8;j++) z[j]=0;
  return z;
}
DEV f32x4 f32x4_zero(){
  f32x4 z;
#pragma unroll
  for(int j=0;j<4;j++) z[j]=0.f;
  return z;
}
DEV f32x4 mfma16(s16x8 a, s16x8 b, f32x4 c){
  return __builtin_amdgcn_mfma_f32_16x16x32_bf16(a, b, c, 0, 0, 0);
}

// ---------------- problem constants ----------------
// B=4, Cin=512 (concat), H=W=64, P=9 taps, Cout=256, M = B*H*W = 16384
// workspace layout (bytes), all 256B-aligned
static constexpr size_t OFF_ACC_B  = 0;                        // float[16384*32]
static constexpr size_t OUT1_ACC_B = 2097152;                  // float[16384*256]
static constexpr size_t OUT2_ACC_B = OUT1_ACC_B + 16777216;    // float[16384*256]
static constexpr size_t STATS_B    = OUT2_ACC_B + 16777216;    // float[1024]
static constexpr size_t ZERO_BYTES = STATS_B + 4096;
static constexpr size_t XN_B       = ZERO_BYTES;               // u16[16384*512]
static constexpr size_t OUT1N_B    = XN_B + 16777216;          // u16[16384*256]
static constexpr size_t WOFFT_B    = OUT1N_B + 8388608;        // u16[32*4608]
static constexpr size_t WDCNT_B    = WOFFT_B + 294912;         // u16[256*4608]
static constexpr size_t W2T_B      = WDCNT_B + 2359296;        // u16[256*2304]
// total ~61.7 MB

// ---------------- NCHW fp32 (concat) -> NHWC bf16 ----------------
__global__ void k_x_to_nhwc(const float* __restrict__ v, const float* __restrict__ vi,
                            u16* __restrict__ xn){
  __shared__ float tile[64][65];
  const int b = blockIdx.z, c0 = blockIdx.y*64, hw0 = blockIdx.x*64;
  const float* src = (c0 < 256) ? (v  + ((size_t)b*256 + c0)      *4096)
                                : (vi + ((size_t)b*256 + (c0-256))*4096);
  const int t = threadIdx.x;
#pragma unroll
  for(int k=0;k<16;k++){
    int idx = t + k*256;
    int cl = idx >> 6, wl = idx & 63;
    tile[cl][wl] = src[(size_t)cl*4096 + hw0 + wl];
  }
  __syncthreads();
#pragma unroll
  for(int k=0;k<16;k++){
    int idx = t + k*256;
    int wl = idx >> 6, cl = idx & 63;
    xn[(size_t)(b*4096 + hw0 + wl)*512 + c0 + cl] = (u16)f2bf(tile[cl][wl]);
  }
}

// ---------------- weight repacks: OIHW fp32 -> [N][K] bf16, K = tap*C + c ----------------
__global__ void k_prep_woff(const float* __restrict__ w, u16* __restrict__ wt){
  int idx = blockIdx.x*256 + threadIdx.x;
  if(idx >= 32*4608) return;
  int n = idx / 4608, k = idx % 4608;
  int t = k >> 9, c = k & 511;
  float val = (n < 27) ? w[(size_t)(n*512 + c)*9 + t] : 0.f;
  wt[idx] = (u16)f2bf(val);
}
__global__ void k_prep_wdcn(const float* __restrict__ w, u16* __restrict__ wt){
  int idx = blockIdx.x*256 + threadIdx.x;
  if(idx >= 256*4608) return;
  int n = idx / 4608, k = idx % 4608;
  int t = k >> 9, c = k & 511;
  wt[idx] = (u16)f2bf(w[(size_t)(n*512 + c)*9 + t]);
}
__global__ void k_prep_w2(const float* __restrict__ w, u16* __restrict__ wt){
  int idx = blockIdx.x*256 + threadIdx.x;
  if(idx >= 256*2304) return;
  int n = idx / 2304, k = idx % 2304;
  int t = k >> 8, c = k & 255;
  wt[idx] = (u16)f2bf(w[(size_t)(n*256 + c)*9 + t]);
}

// ---------------- offset conv: 512ch -> 27(pad 32), implicit GEMM ----------------
// grid (128 m-tiles of 128, 8 k-splits: tap-group {0,2}{2,4}{4,6}{6,9} x ch-half)
__global__ __launch_bounds__(256, 4) void k_conv_off(
    const u16* __restrict__ xn, const u16* __restrict__ wt, float* __restrict__ offa){
  __shared__ short A_lds[4][128][8];   // [k/8][row][8]
  __shared__ short B_lds[4][32][8];
  const int tid = threadIdx.x;
  const int lane = tid & 63, wid = tid >> 6;
  const int quad = lane >> 4, ln = lane & 15;
  const int m0 = blockIdx.x * 128;
  const int b = m0 >> 12;
  const int h0 = (m0 & 4095) >> 6;
  const int ks = blockIdx.y >> 1;
  const int chh = blockIdx.y & 1;
  const int CH0 = chh << 8;
  const int ts0 = (ks == 3) ? 6 : ks*2;
  const int ntap = (ks == 3) ? 3 : 2;
  const int m_base = wid * 32;
  const int r = tid >> 1, sp = (tid & 1) * 2;
  const int h_r = h0 + (r >> 6), w_r = r & 63;
  const s16x8* Ap = (const s16x8*)A_lds;
  const s16x8* Bp = (const s16x8*)B_lds;
  f32x4 acc[2][2];
#pragma unroll
  for(int mf=0;mf<2;mf++)
#pragma unroll
    for(int nf=0;nf<2;nf++) acc[mf][nf] = f32x4_zero();

  s16x8 v0, v1, bv;
  auto load_it = [&](int it){
    const int tp = ts0 + (it >> 3);
    const int ty = tp/3, tx = tp - ty*3;
    const int y = h_r - 1 + ty, x = w_r - 1 + tx;
    const bool vld = (y>=0) & (y<64) & (x>=0) & (x<64);
    const int cA = CH0 + (it & 7)*32;
    v0 = s16x8_zero(); v1 = s16x8_zero();
    if(vld){
      const u16* src = xn + ((size_t)((b<<12) + (y<<6) + x) << 9) + cA + sp*8;
      v0 = *(const s16x8*)(src);
      v1 = *(const s16x8*)(src + 8);
    }
    if(tid < 128){
      const int n = tid & 31, s2 = tid >> 5;
      bv = *(const s16x8*)(wt + (size_t)n*4608 + tp*512 + cA + s2*8);
    }
  };

  const int NIT = ntap * 8;
  load_it(0);
  for(int it = 0; it < NIT; ++it){
    __syncthreads();     // previous iteration's LDS frag reads done
    *(s16x8*)(&A_lds[sp][r][0])   = v0;
    *(s16x8*)(&A_lds[sp+1][r][0]) = v1;
    if(tid < 128){
      const int n = tid & 31, s2 = tid >> 5;
      *(s16x8*)(&B_lds[s2][n][0]) = bv;
    }
    if(it + 1 < NIT) load_it(it + 1);   // prefetch covered by barrier+MFMA phase
    __syncthreads();
    s16x8 a0 = Ap[quad*128 + m_base + ln];
    s16x8 a1 = Ap[quad*128 + m_base + 16 + ln];
    s16x8 b0 = Bp[quad*32 + ln];
    s16x8 b1 = Bp[quad*32 + 16 + ln];
    acc[0][0] = mfma16(a0, b0, acc[0][0]);
    acc[0][1] = mfma16(a0, b1, acc[0][1]);
    acc[1][0] = mfma16(a1, b0, acc[1][0]);
    acc[1][1] = mfma16(a1, b1, acc[1][1]);
  }
#pragma unroll
  for(int mf=0;mf<2;mf++)
#pragma unroll
    for(int nf=0;nf<2;nf++){
      const int col = nf*16 + ln;
#pragma unroll
      for(int i=0;i<4;i++){
        const int row = m_base + mf*16 + quad*4 + i;
        unsafeAtomicAdd(offa + (size_t)(m0+row)*32 + col, acc[mf][nf][i]);
      }
    }
}

// ---------------- DCN main: bilinear-sample A rows, GEMM vs w_dcn ----------------
// grid (256 m-tiles of 64, 4 k-splits: tap-group {0..3}{4..8} x ch-half)
__global__ __launch_bounds__(256, 4) void k_dcn(
    const u16* __restrict__ xn, const u16* __restrict__ wt,
    const float* __restrict__ offa, const float* __restrict__ boff,
    float* __restrict__ outa){
  __shared__ short A_lds[4][64][8];
  __shared__ short B_lds[4][256][8];
  __shared__ int   p_ofs[5][4][64];
  __shared__ float p_wgt[5][4][64];
  const int tid = threadIdx.x;
  const int lane = tid & 63, wid = tid >> 6;
  const int quad = lane >> 4, ln = lane & 15;
  const int m0 = blockIdx.x * 64;
  const int b = m0 >> 12;
  const int h = (m0 & 4095) >> 6;
  const int tg = blockIdx.y >> 1;
  const int chh = blockIdx.y & 1;
  const int CH0 = chh << 8;
  const int ts0 = tg ? 4 : 0;
  const int ntap = tg ? 5 : 4;
  const int wm = wid >> 1, wn = wid & 1;
  const int m_base = wm*32, n_base = wn*128;
  const int r = tid >> 2, sub = tid & 3;
  const s16x8* Ap = (const s16x8*)A_lds;
  const s16x8* Bp = (const s16x8*)B_lds;
  const u16* wrowt = wt + (size_t)tid*4608;
  f32x4 acc[2][8];
#pragma unroll
  for(int mf=0;mf<2;mf++)
#pragma unroll
    for(int nf=0;nf<8;nf++) acc[mf][nf] = f32x4_zero();

  // ---- one-time: bilinear offsets/weights for ALL taps of this block ----
  {
    const int rr = tid & 63;
    const float* orow = offa + (size_t)(m0+rr)*32;
    for(int tpi = tid >> 6; tpi < ntap; tpi += 4){
      const int tp = ts0 + tpi;
      float dy = orow[2*tp]   + boff[2*tp];
      float dx = orow[2*tp+1] + boff[2*tp+1];
      float mz = orow[18+tp]  + boff[18+tp];
      float mk = 1.f / (1.f + expf(-mz));               // modulation mask
      float ypos = (float)(h - 1 + tp/3) + dy;
      float xpos = (float)(rr - 1 + tp%3) + dx;
      float y0f = floorf(ypos), x0f = floorf(xpos);
      float ly = ypos - y0f, lx = xpos - x0f;
      int y0 = (int)y0f, x0 = (int)x0f;
#pragma unroll
      for(int k=0;k<4;k++){
        int ddy = k >> 1, ddx = k & 1;
        int yi = y0 + ddy, xi = x0 + ddx;
        bool vv = (yi >= 0) & (yi < 64) & (xi >= 0) & (xi < 64);
        float wk = (ddy ? ly : 1.f-ly) * (ddx ? lx : 1.f-lx) * mk;
        if(!vv) wk = 0.f;
        int yc = yi < 0 ? 0 : (yi > 63 ? 63 : yi);
        int xc = xi < 0 ? 0 : (xi > 63 ? 63 : xi);
        p_ofs[tpi][k][rr] = ((b << 12) + (yc << 6) + xc) << 9;  // *512 channels
        p_wgt[tpi][k][rr] = wk;
      }
    }
  }
  __syncthreads();

  s16x8 a0, a1, a2, a3, b0, b1, b2, b3;
  float w0, w1, w2, w3;
  auto loadA = [&](int it){
    const int tpi = it >> 3;
    const int c0 = CH0 + (it & 7)*32 + sub*8;
    w0 = p_wgt[tpi][0][r]; w1 = p_wgt[tpi][1][r];
    w2 = p_wgt[tpi][2][r]; w3 = p_wgt[tpi][3][r];
    a0 = *(const s16x8*)(xn + p_ofs[tpi][0][r] + c0);
    a1 = *(const s16x8*)(xn + p_ofs[tpi][1][r] + c0);
    a2 = *(const s16x8*)(xn + p_ofs[tpi][2][r] + c0);
    a3 = *(const s16x8*)(xn + p_ofs[tpi][3][r] + c0);
  };
  auto loadB = [&](int it){
    const int kb = (ts0 + (it >> 3))*512 + CH0 + (it & 7)*32;
    b0 = *(const s16x8*)(wrowt + kb);
    b1 = *(const s16x8*)(wrowt + kb + 8);
    b2 = *(const s16x8*)(wrowt + kb + 16);
    b3 = *(const s16x8*)(wrowt + kb + 24);
  };

  const int NIT = ntap * 8;
  loadA(0); loadB(0);
  for(int it = 0; it < NIT; ++it){
    // blend the 4 bilinear neighbors for this 32-channel chunk (consumes a*, w*)
    s16x8 pk;
#pragma unroll
    for(int j=0;j<8;j++){
      float f = w0 * bf2f(a0[j]);
      f = fmaf(w1, bf2f(a1[j]), f);
      f = fmaf(w2, bf2f(a2[j]), f);
      f = fmaf(w3, bf2f(a3[j]), f);
      pk[j] = f2bf(f);
    }
    const bool more = (it + 1 < NIT);
    if(more) loadA(it + 1);            // A regs free; latency hidden by barrier+LDS+MFMA
    __syncthreads();                   // previous iteration's LDS frag reads done
    *(s16x8*)(&A_lds[sub][r][0]) = pk;
    *(s16x8*)(&B_lds[0][tid][0]) = b0;
    *(s16x8*)(&B_lds[1][tid][0]) = b1;
    *(s16x8*)(&B_lds[2][tid][0]) = b2;
    *(s16x8*)(&B_lds[3][tid][0]) = b3;
    if(more) loadB(it + 1);            // B regs consumed by ds_write above
    __syncthreads();
    s16x8 af0 = Ap[quad*64 + m_base + ln];
    s16x8 af1 = Ap[quad*64 + m_base + 16 + ln];
    s16x8 bfr[8];
#pragma unroll
    for(int nf=0;nf<8;nf++) bfr[nf] = Bp[quad*256 + n_base + nf*16 + ln];
#pragma unroll
    for(int nf=0;nf<8;nf++){
      acc[0][nf] = mfma16(af0, bfr[nf], acc[0][nf]);
      acc[1][nf] = mfma16(af1, bfr[nf], acc[1][nf]);
    }
  }
#pragma unroll
  for(int mf=0;mf<2;mf++)
#pragma unroll
    for(int nf=0;nf<8;nf++){
      const int col = n_base + nf*16 + ln;
#pragma unroll
      for(int i=0;i<4;i++){
        const int row = m_base + mf*16 + quad*4 + i;
        unsafeAtomicAdd(outa + (size_t)(m0+row)*256 + col, acc[mf][nf][i]);
      }
    }
}

// ---------------- conv2: 256 -> 256, implicit GEMM on normalized out1 ----------------
// grid (256 m-tiles of 64, 4 k-splits: tap-group {0..3}{4..8} x ch-half)
__global__ __launch_bounds__(256, 4) void k_conv2(
    const u16* __restrict__ a_in, const u16* __restrict__ wt, float* __restrict__ outa){
  __shared__ short A_lds[4][64][8];
  __shared__ short B_lds[4][256][8];
  const int tid = threadIdx.x;
  const int lane = tid & 63, wid = tid >> 6;
  const int quad = lane >> 4, ln = lane & 15;
  const int m0 = blockIdx.x * 64;
  const int b = m0 >> 12;
  const int h = (m0 & 4095) >> 6;
  const int tg = blockIdx.y >> 1;
  const int chh = blockIdx.y & 1;
  const int CH0 = chh << 7;
  const int ts0 = tg ? 4 : 0;
  const int ntap = tg ? 5 : 4;
  const int wm = wid >> 1, wn = wid & 1;
  const int m_base = wm*32, n_base = wn*128;
  const int r = tid >> 2, sub = tid & 3;
  const s16x8* Ap = (const s16x8*)A_lds;
  const s16x8* Bp = (const s16x8*)B_lds;
  const u16* wrowt = wt + (size_t)tid*2304;
  f32x4 acc[2][8];
#pragma unroll
  for(int mf=0;mf<2;mf++)
#pragma unroll
    for(int nf=0;nf<8;nf++) acc[mf][nf] = f32x4_zero();

  s16x8 va, b0, b1, b2, b3;
  auto load_it = [&](int it){
    const int tp = ts0 + (it >> 2);
    const int ty = tp/3, tx = tp - ty*3;
    const int y = h - 1 + ty, x = r - 1 + tx;
    const bool vld = (y>=0) & (y<64) & (x>=0) & (x<64);
    const int c0 = CH0 + (it & 3)*32;
    va = s16x8_zero();
    if(vld) va = *(const s16x8*)(a_in + (((size_t)((b<<12) + (y<<6) + x)) << 8) + c0 + sub*8);
    const int kb = tp*256 + c0;
    b0 = *(const s16x8*)(wrowt + kb);
    b1 = *(const s16x8*)(wrowt + kb + 8);
    b2 = *(const s16x8*)(wrowt + kb + 16);
    b3 = *(const s16x8*)(wrowt + kb + 24);
  };

  const int NIT = ntap * 4;
  load_it(0);
  for(int it = 0; it < NIT; ++it){
    __syncthreads();     // previous iteration's LDS frag reads done
    *(s16x8*)(&A_lds[sub][r][0]) = va;
    *(s16x8*)(&B_lds[0][tid][0]) = b0;
    *(s16x8*)(&B_lds[1][tid][0]) = b1;
    *(s16x8*)(&B_lds[2][tid][0]) = b2;
    *(s16x8*)(&B_lds[3][tid][0]) = b3;
    if(it + 1 < NIT) load_it(it + 1);  // prefetch next chunk into regs
    __syncthreads();
    s16x8 af0 = Ap[quad*64 + m_base + ln];
    s16x8 af1 = Ap[quad*64 + m_base + 16 + ln];
    s16x8 bfr[8];
#pragma unroll
    for(int nf=0;nf<8;nf++) bfr[nf] = Bp[quad*256 + n_base + nf*16 + ln];
#pragma unroll
    for(int nf=0;nf<8;nf++){
      acc[0][nf] = mfma16(af0, bfr[nf], acc[0][nf]);
      acc[1][nf] = mfma16(af1, bfr[nf], acc[1][nf]);
    }
  }
#pragma unroll
  for(int mf=0;mf<2;mf++)
#pragma unroll
    for(int nf=0;nf<8;nf++){
      const int col = n_base + nf*16 + ln;
#pragma unroll
      for(int i=0;i<4;i++){
        const int row = m_base + mf*16 + quad*4 + i;
        unsafeAtomicAdd(outa + (size_t)(m0+row)*256 + col, acc[mf][nf][i]);
      }
    }
}

// ---------------- BN stats: per-channel sum/sumsq over M=16384 ----------------
__global__ void k_stats(const float* __restrict__ acc, float* __restrict__ sum,
                        float* __restrict__ sq){
  const int m0 = blockIdx.x*64;
  const int c = threadIdx.x;
  float s = 0.f, q = 0.f;
  for(int i=0;i<64;i++){
    float v = acc[(size_t)(m0+i)*256 + c];
    s += v; q += v*v;
  }
  unsafeAtomicAdd(sum + c, s);
  unsafeAtomicAdd(sq + c, q);
}

// ---------------- BN1 + ReLU -> bf16 NHWC ----------------
__global__ void k_bn1(const float* __restrict__ acc, const float* __restrict__ sum,
                      const float* __restrict__ sq, const float* __restrict__ g,
                      const float* __restrict__ bt, u16* __restrict__ o){
  __shared__ float sc[256], sh[256];
  const int t = threadIdx.x;
  {
    float mean = sum[t] * (1.f/16384.f);
    float var  = sq[t] * (1.f/16384.f) - mean*mean;
    float rstd = rsqrtf(var + 1e-5f);
    float s = g[t] * rstd;
    sc[t] = s; sh[t] = bt[t] - mean*s;
  }
  __syncthreads();
  const int c4 = (t & 63) * 4;
  const float s0 = sc[c4], s1 = sc[c4+1], s2 = sc[c4+2], s3 = sc[c4+3];
  const float h0 = sh[c4], h1 = sh[c4+1], h2 = sh[c4+2], h3 = sh[c4+3];
#pragma unroll
  for(int k=0;k<4;k++){
    int m = blockIdx.x*16 + k*4 + (t>>6);
    const float4 v = *(const float4*)(acc + (size_t)m*256 + c4);
    unsigned int lo = (unsigned int)(u16)f2bf(fmaxf(0.f, v.x*s0 + h0))
                    | ((unsigned int)(u16)f2bf(fmaxf(0.f, v.y*s1 + h1)) << 16);
    unsigned int hi = (unsigned int)(u16)f2bf(fmaxf(0.f, v.z*s2 + h2))
                    | ((unsigned int)(u16)f2bf(fmaxf(0.f, v.w*s3 + h3)) << 16);
    uint2 pr; pr.x = lo; pr.y = hi;
    *(uint2*)(o + (size_t)m*256 + c4) = pr;
  }
}

// ---------------- BN2 + ReLU + NHWC->NCHW fp32 output ----------------
__global__ void k_bn2_out(const float* __restrict__ acc, const float* __restrict__ sum,
                          const float* __restrict__ sq, const float* __restrict__ g,
                          const float* __restrict__ bt, float* __restrict__ out){
  __shared__ float tile[64][65];
  __shared__ float sc[64], sh[64];
  const int t = threadIdx.x;
  const int b = blockIdx.z, c0 = blockIdx.y*64, hw0 = blockIdx.x*64;
  if(t < 64){
    int c = c0 + t;
    float mean = sum[c] * (1.f/16384.f);
    float var  = sq[c] * (1.f/16384.f) - mean*mean;
    float rstd = rsqrtf(var + 1e-5f);
    float s = g[c] * rstd;
    sc[t] = s; sh[t] = bt[c] - mean*s;
  }
  __syncthreads();
#pragma unroll
  for(int k=0;k<16;k++){
    int idx = t + k*256;
    int wl = idx >> 6, cl = idx & 63;
    float v = acc[(size_t)((b<<12) + hw0 + wl)*256 + c0 + cl];
    tile[wl][cl] = fmaxf(0.f, v*sc[cl] + sh[cl]);
  }
  __syncthreads();
#pragma unroll
  for(int k=0;k<16;k++){
    int idx = t + k*256;
    int cl = idx >> 6, wl = idx & 63;
    out[(size_t)(b*256 + c0 + cl)*4096 + hw0 + wl] = tile[wl][cl];
  }
}

extern "C" void kernel_launch(void* const* d_in, const int* in_sizes, int n_in,
                              void* d_out, int out_size, void* d_ws, size_t ws_size,
                              hipStream_t stream){
  const float* in_v  = (const float*)d_in[0];
  const float* in_i  = (const float*)d_in[1];
  const float* w_off = (const float*)d_in[2];
  const float* b_off = (const float*)d_in[3];
  const float* w_dcn = (const float*)d_in[4];
  const float* g1    = (const float*)d_in[5];
  const float* bt1   = (const float*)d_in[6];
  const float* w2    = (const float*)d_in[7];
  const float* g2    = (const float*)d_in[8];
  const float* bt2   = (const float*)d_in[9];
  float* out = (float*)d_out;
  char* ws = (char*)d_ws;

  float* off_acc  = (float*)(ws + OFF_ACC_B);
  float* out1_acc = (float*)(ws + OUT1_ACC_B);
  float* out2_acc = (float*)(ws + OUT2_ACC_B);
  float* stats    = (float*)(ws + STATS_B);
  float* sum1 = stats,       *sq1 = stats + 256;
  float* sum2 = stats + 512, *sq2 = stats + 768;
  u16* xn    = (u16*)(ws + XN_B);
  u16* out1n = (u16*)(ws + OUT1N_B);
  u16* wofft = (u16*)(ws + WOFFT_B);
  u16* wdcnt = (u16*)(ws + WDCNT_B);
  u16* w2t   = (u16*)(ws + W2T_B);

  hipMemsetAsync(ws, 0, ZERO_BYTES, stream);
  k_x_to_nhwc<<<dim3(64,8,4), 256, 0, stream>>>(in_v, in_i, xn);
  k_prep_woff<<<576, 256, 0, stream>>>(w_off, wofft);
  k_prep_wdcn<<<4608, 256, 0, stream>>>(w_dcn, wdcnt);
  k_prep_w2<<<2304, 256, 0, stream>>>(w2, w2t);
  k_conv_off<<<dim3(128,8), 256, 0, stream>>>(xn, wofft, off_acc);
  k_dcn<<<dim3(256,4), 256, 0, stream>>>(xn, wdcnt, off_acc, b_off, out1_acc);
  k_stats<<<256, 256, 0, stream>>>(out1_acc, sum1, sq1);
  k_bn1<<<1024, 256, 0, stream>>>(out1_acc, sum1, sq1, g1, bt1, out1n);
  k_conv2<<<dim3(256,4), 256, 0, stream>>>(out1n, w2t, out2_acc);
  k_stats<<<256, 256, 0, stream>>>(out2_acc, sum2, sq2);
  k_bn2_out<<<dim3(64,4,4), 256, 0, stream>>>(out2_acc, sum2, sq2, g2, bt2, out);
}

// Round 2
// 352.650 us; speedup vs baseline: 1.1256x; 1.1256x over previous
//
#include <hip/hip_runtime.h>
#include <cstdint>
#include <cstddef>

typedef unsigned short u16;
typedef __attribute__((ext_vector_type(8))) short s16x8;
typedef __attribute__((ext_vector_type(4))) float f32x4;

#define DEV __device__ __forceinline__

DEV float bf2f(short u){
  union { unsigned int i; float f; } v;
  v.i = ((unsigned int)(u16)u) << 16;
  return v.f;
}
DEV short f2bf(float f){
  union { float f; unsigned int i; } v; v.f = f;
  unsigned int u = v.i;
  u += 0x7fffu + ((u >> 16) & 1u);   // RNE
  return (short)(u >> 16);
}
DEV s16x8 s16x8_zero(){
  s16x8 z;
#pragma unroll
  for(int j=0;j<8;j++) z[j]=0;
  return z;
}
DEV f32x4 f32x4_zero(){
  f32x4 z;
#pragma unroll
  for(int j=0;j<4;j++) z[j]=0.f;
  return z;
}
DEV f32x4 mfma16(s16x8 a, s16x8 b, f32x4 c){
  return __builtin_amdgcn_mfma_f32_16x16x32_bf16(a, b, c, 0, 0, 0);
}

// ---------------- problem constants ----------------
// B=4, Cin=512 (concat), H=W=64, P=9 taps, Cout=256, M = B*H*W = 16384
// workspace layout (bytes), all 256B-aligned
static constexpr size_t OFF_ACC_B  = 0;                        // float[16384*32]
static constexpr size_t OUT1_ACC_B = 2097152;                  // float[16384*256]
static constexpr size_t OUT2_ACC_B = OUT1_ACC_B + 16777216;    // float[16384*256]
static constexpr size_t STATS_B    = OUT2_ACC_B + 16777216;    // float[1024]
static constexpr size_t ZERO_BYTES = STATS_B + 4096;
static constexpr size_t XN_B       = ZERO_BYTES;               // u16[16384*512]
static constexpr size_t OUT1N_B    = XN_B + 16777216;          // u16[16384*256]
static constexpr size_t WOFFT_B    = OUT1N_B + 8388608;        // u16[32*4608]
static constexpr size_t WDCNT_B    = WOFFT_B + 294912;         // u16[256*4608]
static constexpr size_t W2T_B      = WDCNT_B + 2359296;        // u16[256*2304]
// total ~61.7 MB

// ---------------- NCHW fp32 (concat) -> NHWC bf16 ----------------
__global__ void k_x_to_nhwc(const float* __restrict__ v, const float* __restrict__ vi,
                            u16* __restrict__ xn){
  __shared__ float tile[64][65];
  const int b = blockIdx.z, c0 = blockIdx.y*64, hw0 = blockIdx.x*64;
  const float* src = (c0 < 256) ? (v  + ((size_t)b*256 + c0)      *4096)
                                : (vi + ((size_t)b*256 + (c0-256))*4096);
  const int t = threadIdx.x;
#pragma unroll
  for(int k=0;k<16;k++){
    int idx = t + k*256;
    int cl = idx >> 6, wl = idx & 63;
    tile[cl][wl] = src[(size_t)cl*4096 + hw0 + wl];
  }
  __syncthreads();
#pragma unroll
  for(int k=0;k<16;k++){
    int idx = t + k*256;
    int wl = idx >> 6, cl = idx & 63;
    xn[(size_t)(b*4096 + hw0 + wl)*512 + c0 + cl] = (u16)f2bf(tile[cl][wl]);
  }
}

// ---------------- weight repacks: OIHW fp32 -> [N][K] bf16, K = tap*C + c ----------------
__global__ void k_prep_woff(const float* __restrict__ w, u16* __restrict__ wt){
  int idx = blockIdx.x*256 + threadIdx.x;
  if(idx >= 32*4608) return;
  int n = idx / 4608, k = idx % 4608;
  int t = k >> 9, c = k & 511;
  float val = (n < 27) ? w[(size_t)(n*512 + c)*9 + t] : 0.f;
  wt[idx] = (u16)f2bf(val);
}
__global__ void k_prep_wdcn(const float* __restrict__ w, u16* __restrict__ wt){
  int idx = blockIdx.x*256 + threadIdx.x;
  if(idx >= 256*4608) return;
  int n = idx / 4608, k = idx % 4608;
  int t = k >> 9, c = k & 511;
  wt[idx] = (u16)f2bf(w[(size_t)(n*512 + c)*9 + t]);
}
__global__ void k_prep_w2(const float* __restrict__ w, u16* __restrict__ wt){
  int idx = blockIdx.x*256 + threadIdx.x;
  if(idx >= 256*2304) return;
  int n = idx / 2304, k = idx % 2304;
  int t = k >> 8, c = k & 255;
  wt[idx] = (u16)f2bf(w[(size_t)(n*256 + c)*9 + t]);
}

// ---------------- offset conv: 512ch -> 27(pad 32), implicit GEMM ----------------
// grid (128 m-tiles of 128, 4 k-splits by taps {0,2}{2,4}{4,6}{6,9}); depth-2 prefetch
__global__ __launch_bounds__(256, 2) void k_conv_off(
    const u16* __restrict__ xn, const u16* __restrict__ wt, float* __restrict__ offa){
  __shared__ short A_lds[4][128][8];   // [k/8][row][8]
  __shared__ short B_lds[4][32][8];
  const int tid = threadIdx.x;
  const int lane = tid & 63, wid = tid >> 6;
  const int quad = lane >> 4, ln = lane & 15;
  const int m0 = blockIdx.x * 128;
  const int b = m0 >> 12;
  const int h0 = (m0 & 4095) >> 6;
  const int ks = blockIdx.y;
  const int ts0 = (ks == 3) ? 6 : ks*2;
  const int ntap = (ks == 3) ? 3 : 2;
  const int m_base = wid * 32;
  const int r = tid >> 1, sp = (tid & 1) * 2;
  const int h_r = h0 + (r >> 6), w_r = r & 63;
  const s16x8* Ap = (const s16x8*)A_lds;
  const s16x8* Bp = (const s16x8*)B_lds;
  f32x4 acc[2][2];
#pragma unroll
  for(int mf=0;mf<2;mf++)
#pragma unroll
    for(int nf=0;nf<2;nf++) acc[mf][nf] = f32x4_zero();

  auto load_it = [&](int it, s16x8& v0, s16x8& v1, s16x8& bv){
    const int tp = ts0 + (it >> 4);
    const int cA = (it & 15)*32;
    const int ty = tp/3, tx = tp - ty*3;
    const int y = h_r - 1 + ty, x = w_r - 1 + tx;
    const bool vld = (y>=0) & (y<64) & (x>=0) & (x<64);
    v0 = s16x8_zero(); v1 = s16x8_zero();
    if(vld){
      const u16* src = xn + ((size_t)((b<<12) + (y<<6) + x) << 9) + cA + sp*8;
      v0 = *(const s16x8*)(src);
      v1 = *(const s16x8*)(src + 8);
    }
    if(tid < 128){
      const int n = tid & 31, s2 = tid >> 5;
      bv = *(const s16x8*)(wt + (size_t)n*4608 + tp*512 + cA + s2*8);
    }
  };

  const int NIT = ntap * 16;      // 32 or 48 (always even)
  s16x8 v0a, v1a, bva, v0b, v1b, bvb;
  bva = s16x8_zero(); bvb = s16x8_zero();
  load_it(0, v0a, v1a, bva);
  load_it(1, v0b, v1b, bvb);
  for(int it = 0; it < NIT; it += 2){
    // ---- even sub-iter: consume set A, prefetch it+2 into set A
    __syncthreads();
    *(s16x8*)(&A_lds[sp][r][0])   = v0a;
    *(s16x8*)(&A_lds[sp+1][r][0]) = v1a;
    if(tid < 128){
      const int n = tid & 31, s2 = tid >> 5;
      *(s16x8*)(&B_lds[s2][n][0]) = bva;
    }
    if(it + 2 < NIT) load_it(it + 2, v0a, v1a, bva);
    __syncthreads();
    {
      s16x8 a0 = Ap[quad*128 + m_base + ln];
      s16x8 a1 = Ap[quad*128 + m_base + 16 + ln];
      s16x8 b0 = Bp[quad*32 + ln];
      s16x8 b1 = Bp[quad*32 + 16 + ln];
      acc[0][0] = mfma16(a0, b0, acc[0][0]);
      acc[0][1] = mfma16(a0, b1, acc[0][1]);
      acc[1][0] = mfma16(a1, b0, acc[1][0]);
      acc[1][1] = mfma16(a1, b1, acc[1][1]);
    }
    // ---- odd sub-iter: consume set B, prefetch it+3 into set B
    __syncthreads();
    *(s16x8*)(&A_lds[sp][r][0])   = v0b;
    *(s16x8*)(&A_lds[sp+1][r][0]) = v1b;
    if(tid < 128){
      const int n = tid & 31, s2 = tid >> 5;
      *(s16x8*)(&B_lds[s2][n][0]) = bvb;
    }
    if(it + 3 < NIT) load_it(it + 3, v0b, v1b, bvb);
    __syncthreads();
    {
      s16x8 a0 = Ap[quad*128 + m_base + ln];
      s16x8 a1 = Ap[quad*128 + m_base + 16 + ln];
      s16x8 b0 = Bp[quad*32 + ln];
      s16x8 b1 = Bp[quad*32 + 16 + ln];
      acc[0][0] = mfma16(a0, b0, acc[0][0]);
      acc[0][1] = mfma16(a0, b1, acc[0][1]);
      acc[1][0] = mfma16(a1, b0, acc[1][0]);
      acc[1][1] = mfma16(a1, b1, acc[1][1]);
    }
  }
#pragma unroll
  for(int mf=0;mf<2;mf++)
#pragma unroll
    for(int nf=0;nf<2;nf++){
      const int col = nf*16 + ln;
#pragma unroll
      for(int i=0;i<4;i++){
        const int row = m_base + mf*16 + quad*4 + i;
        unsafeAtomicAdd(offa + (size_t)(m0+row)*32 + col, acc[mf][nf][i]);
      }
    }
}

// ---------------- DCN main: bilinear-sample A rows, GEMM vs w_dcn ----------------
// grid (256 m-tiles of 64, 2 k-splits by taps {0..3},{4..8}); depth-2 prefetch
__global__ __launch_bounds__(256, 2) void k_dcn(
    const u16* __restrict__ xn, const u16* __restrict__ wt,
    const float* __restrict__ offa, const float* __restrict__ boff,
    float* __restrict__ outa){
  __shared__ short A_lds[4][64][8];
  __shared__ short B_lds[4][256][8];
  __shared__ int   p_ofs[5][4][64];
  __shared__ float p_wgt[5][4][64];
  const int tid = threadIdx.x;
  const int lane = tid & 63, wid = tid >> 6;
  const int quad = lane >> 4, ln = lane & 15;
  const int m0 = blockIdx.x * 64;
  const int b = m0 >> 12;
  const int h = (m0 & 4095) >> 6;
  const int tg = blockIdx.y;
  const int ts0 = tg ? 4 : 0;
  const int ntap = tg ? 5 : 4;
  const int wm = wid >> 1, wn = wid & 1;
  const int m_base = wm*32, n_base = wn*128;
  const int r = tid >> 2, sub = tid & 3;
  const s16x8* Ap = (const s16x8*)A_lds;
  const s16x8* Bp = (const s16x8*)B_lds;
  const u16* wrowt = wt + (size_t)tid*4608;
  f32x4 acc[2][8];
#pragma unroll
  for(int mf=0;mf<2;mf++)
#pragma unroll
    for(int nf=0;nf<8;nf++) acc[mf][nf] = f32x4_zero();

  // ---- one-time: bilinear offsets/weights for ALL taps of this block ----
  {
    const int rr = tid & 63;
    const float* orow = offa + (size_t)(m0+rr)*32;
    for(int tpi = tid >> 6; tpi < ntap; tpi += 4){
      const int tp = ts0 + tpi;
      float dy = orow[2*tp]   + boff[2*tp];
      float dx = orow[2*tp+1] + boff[2*tp+1];
      float mz = orow[18+tp]  + boff[18+tp];
      float mk = 1.f / (1.f + expf(-mz));               // modulation mask
      float ypos = (float)(h - 1 + tp/3) + dy;
      float xpos = (float)(rr - 1 + tp%3) + dx;
      float y0f = floorf(ypos), x0f = floorf(xpos);
      float ly = ypos - y0f, lx = xpos - x0f;
      int y0 = (int)y0f, x0 = (int)x0f;
#pragma unroll
      for(int k=0;k<4;k++){
        int ddy = k >> 1, ddx = k & 1;
        int yi = y0 + ddy, xi = x0 + ddx;
        bool vv = (yi >= 0) & (yi < 64) & (xi >= 0) & (xi < 64);
        float wk = (ddy ? ly : 1.f-ly) * (ddx ? lx : 1.f-lx) * mk;
        if(!vv) wk = 0.f;
        int yc = yi < 0 ? 0 : (yi > 63 ? 63 : yi);
        int xc = xi < 0 ? 0 : (xi > 63 ? 63 : xi);
        p_ofs[tpi][k][rr] = ((b << 12) + (yc << 6) + xc) << 9;  // *512 channels
        p_wgt[tpi][k][rr] = wk;
      }
    }
  }
  __syncthreads();

  auto loadA = [&](int it, s16x8& a0, s16x8& a1, s16x8& a2, s16x8& a3,
                   float& w0, float& w1, float& w2, float& w3){
    const int tpi = it >> 4;
    const int c0 = (it & 15)*32 + sub*8;
    w0 = p_wgt[tpi][0][r]; w1 = p_wgt[tpi][1][r];
    w2 = p_wgt[tpi][2][r]; w3 = p_wgt[tpi][3][r];
    a0 = *(const s16x8*)(xn + p_ofs[tpi][0][r] + c0);
    a1 = *(const s16x8*)(xn + p_ofs[tpi][1][r] + c0);
    a2 = *(const s16x8*)(xn + p_ofs[tpi][2][r] + c0);
    a3 = *(const s16x8*)(xn + p_ofs[tpi][3][r] + c0);
  };
  auto loadB = [&](int it, s16x8& b0, s16x8& b1, s16x8& b2, s16x8& b3){
    const int kb = (ts0 + (it >> 4))*512 + (it & 15)*32;
    b0 = *(const s16x8*)(wrowt + kb);
    b1 = *(const s16x8*)(wrowt + kb + 8);
    b2 = *(const s16x8*)(wrowt + kb + 16);
    b3 = *(const s16x8*)(wrowt + kb + 24);
  };
  auto blend = [&](const s16x8& a0, const s16x8& a1, const s16x8& a2, const s16x8& a3,
                   float w0, float w1, float w2, float w3){
    s16x8 pk;
#pragma unroll
    for(int j=0;j<8;j++){
      float f = w0 * bf2f(a0[j]);
      f = fmaf(w1, bf2f(a1[j]), f);
      f = fmaf(w2, bf2f(a2[j]), f);
      f = fmaf(w3, bf2f(a3[j]), f);
      pk[j] = f2bf(f);
    }
    return pk;
  };

  const int NIT = ntap * 16;   // 64 or 80 (always even)
  s16x8 aA0,aA1,aA2,aA3, bA0,bA1,bA2,bA3;
  s16x8 aB0,aB1,aB2,aB3, bB0,bB1,bB2,bB3;
  float wA0,wA1,wA2,wA3, wB0,wB1,wB2,wB3;
  loadA(0, aA0,aA1,aA2,aA3, wA0,wA1,wA2,wA3);
  loadB(0, bA0,bA1,bA2,bA3);
  loadA(1, aB0,aB1,aB2,aB3, wB0,wB1,wB2,wB3);
  loadB(1, bB0,bB1,bB2,bB3);

  for(int it = 0; it < NIT; it += 2){
    // ---- even sub-iter: set A
    {
      s16x8 pk = blend(aA0,aA1,aA2,aA3, wA0,wA1,wA2,wA3);
      if(it + 2 < NIT) loadA(it + 2, aA0,aA1,aA2,aA3, wA0,wA1,wA2,wA3);
      __syncthreads();
      *(s16x8*)(&A_lds[sub][r][0]) = pk;
      *(s16x8*)(&B_lds[0][tid][0]) = bA0;
      *(s16x8*)(&B_lds[1][tid][0]) = bA1;
      *(s16x8*)(&B_lds[2][tid][0]) = bA2;
      *(s16x8*)(&B_lds[3][tid][0]) = bA3;
      if(it + 2 < NIT) loadB(it + 2, bA0,bA1,bA2,bA3);
      __syncthreads();
      s16x8 af0 = Ap[quad*64 + m_base + ln];
      s16x8 af1 = Ap[quad*64 + m_base + 16 + ln];
      s16x8 bfr[8];
#pragma unroll
      for(int nf=0;nf<8;nf++) bfr[nf] = Bp[quad*256 + n_base + nf*16 + ln];
#pragma unroll
      for(int nf=0;nf<8;nf++){
        acc[0][nf] = mfma16(af0, bfr[nf], acc[0][nf]);
        acc[1][nf] = mfma16(af1, bfr[nf], acc[1][nf]);
      }
    }
    // ---- odd sub-iter: set B
    {
      s16x8 pk = blend(aB0,aB1,aB2,aB3, wB0,wB1,wB2,wB3);
      if(it + 3 < NIT) loadA(it + 3, aB0,aB1,aB2,aB3, wB0,wB1,wB2,wB3);
      __syncthreads();
      *(s16x8*)(&A_lds[sub][r][0]) = pk;
      *(s16x8*)(&B_lds[0][tid][0]) = bB0;
      *(s16x8*)(&B_lds[1][tid][0]) = bB1;
      *(s16x8*)(&B_lds[2][tid][0]) = bB2;
      *(s16x8*)(&B_lds[3][tid][0]) = bB3;
      if(it + 3 < NIT) loadB(it + 3, bB0,bB1,bB2,bB3);
      __syncthreads();
      s16x8 af0 = Ap[quad*64 + m_base + ln];
      s16x8 af1 = Ap[quad*64 + m_base + 16 + ln];
      s16x8 bfr[8];
#pragma unroll
      for(int nf=0;nf<8;nf++) bfr[nf] = Bp[quad*256 + n_base + nf*16 + ln];
#pragma unroll
      for(int nf=0;nf<8;nf++){
        acc[0][nf] = mfma16(af0, bfr[nf], acc[0][nf]);
        acc[1][nf] = mfma16(af1, bfr[nf], acc[1][nf]);
      }
    }
  }
#pragma unroll
  for(int mf=0;mf<2;mf++)
#pragma unroll
    for(int nf=0;nf<8;nf++){
      const int col = n_base + nf*16 + ln;
#pragma unroll
      for(int i=0;i<4;i++){
        const int row = m_base + mf*16 + quad*4 + i;
        unsafeAtomicAdd(outa + (size_t)(m0+row)*256 + col, acc[mf][nf][i]);
      }
    }
}

// ---------------- conv2: 256 -> 256, implicit GEMM on normalized out1 ----------------
// grid (256 m-tiles of 64, 2 k-splits by taps {0..3},{4..8}); depth-2 prefetch
__global__ __launch_bounds__(256, 2) void k_conv2(
    const u16* __restrict__ a_in, const u16* __restrict__ wt, float* __restrict__ outa){
  __shared__ short A_lds[4][64][8];
  __shared__ short B_lds[4][256][8];
  const int tid = threadIdx.x;
  const int lane = tid & 63, wid = tid >> 6;
  const int quad = lane >> 4, ln = lane & 15;
  const int m0 = blockIdx.x * 64;
  const int b = m0 >> 12;
  const int h = (m0 & 4095) >> 6;
  const int tg = blockIdx.y;
  const int ts0 = tg ? 4 : 0;
  const int ntap = tg ? 5 : 4;
  const int wm = wid >> 1, wn = wid & 1;
  const int m_base = wm*32, n_base = wn*128;
  const int r = tid >> 2, sub = tid & 3;
  const s16x8* Ap = (const s16x8*)A_lds;
  const s16x8* Bp = (const s16x8*)B_lds;
  const u16* wrowt = wt + (size_t)tid*2304;
  f32x4 acc[2][8];
#pragma unroll
  for(int mf=0;mf<2;mf++)
#pragma unroll
    for(int nf=0;nf<8;nf++) acc[mf][nf] = f32x4_zero();

  auto load_it = [&](int it, s16x8& va, s16x8& b0, s16x8& b1, s16x8& b2, s16x8& b3){
    const int tp = ts0 + (it >> 3);
    const int c0 = (it & 7)*32;
    const int ty = tp/3, tx = tp - ty*3;
    const int y = h - 1 + ty, x = r - 1 + tx;
    const bool vld = (y>=0) & (y<64) & (x>=0) & (x<64);
    va = s16x8_zero();
    if(vld) va = *(const s16x8*)(a_in + (((size_t)((b<<12) + (y<<6) + x)) << 8) + c0 + sub*8);
    const int kb = tp*256 + c0;
    b0 = *(const s16x8*)(wrowt + kb);
    b1 = *(const s16x8*)(wrowt + kb + 8);
    b2 = *(const s16x8*)(wrowt + kb + 16);
    b3 = *(const s16x8*)(wrowt + kb + 24);
  };

  const int NIT = ntap * 8;    // 32 or 40 (always even)
  s16x8 vA, bA0,bA1,bA2,bA3;
  s16x8 vB, bB0,bB1,bB2,bB3;
  load_it(0, vA, bA0,bA1,bA2,bA3);
  load_it(1, vB, bB0,bB1,bB2,bB3);
  for(int it = 0; it < NIT; it += 2){
    // ---- even sub-iter: set A
    __syncthreads();
    *(s16x8*)(&A_lds[sub][r][0]) = vA;
    *(s16x8*)(&B_lds[0][tid][0]) = bA0;
    *(s16x8*)(&B_lds[1][tid][0]) = bA1;
    *(s16x8*)(&B_lds[2][tid][0]) = bA2;
    *(s16x8*)(&B_lds[3][tid][0]) = bA3;
    if(it + 2 < NIT) load_it(it + 2, vA, bA0,bA1,bA2,bA3);
    __syncthreads();
    {
      s16x8 af0 = Ap[quad*64 + m_base + ln];
      s16x8 af1 = Ap[quad*64 + m_base + 16 + ln];
      s16x8 bfr[8];
#pragma unroll
      for(int nf=0;nf<8;nf++) bfr[nf] = Bp[quad*256 + n_base + nf*16 + ln];
#pragma unroll
      for(int nf=0;nf<8;nf++){
        acc[0][nf] = mfma16(af0, bfr[nf], acc[0][nf]);
        acc[1][nf] = mfma16(af1, bfr[nf], acc[1][nf]);
      }
    }
    // ---- odd sub-iter: set B
    __syncthreads();
    *(s16x8*)(&A_lds[sub][r][0]) = vB;
    *(s16x8*)(&B_lds[0][tid][0]) = bB0;
    *(s16x8*)(&B_lds[1][tid][0]) = bB1;
    *(s16x8*)(&B_lds[2][tid][0]) = bB2;
    *(s16x8*)(&B_lds[3][tid][0]) = bB3;
    if(it + 3 < NIT) load_it(it + 3, vB, bB0,bB1,bB2,bB3);
    __syncthreads();
    {
      s16x8 af0 = Ap[quad*64 + m_base + ln];
      s16x8 af1 = Ap[quad*64 + m_base + 16 + ln];
      s16x8 bfr[8];
#pragma unroll
      for(int nf=0;nf<8;nf++) bfr[nf] = Bp[quad*256 + n_base + nf*16 + ln];
#pragma unroll
      for(int nf=0;nf<8;nf++){
        acc[0][nf] = mfma16(af0, bfr[nf], acc[0][nf]);
        acc[1][nf] = mfma16(af1, bfr[nf], acc[1][nf]);
      }
    }
  }
#pragma unroll
  for(int mf=0;mf<2;mf++)
#pragma unroll
    for(int nf=0;nf<8;nf++){
      const int col = n_base + nf*16 + ln;
#pragma unroll
      for(int i=0;i<4;i++){
        const int row = m_base + mf*16 + quad*4 + i;
        unsafeAtomicAdd(outa + (size_t)(m0+row)*256 + col, acc[mf][nf][i]);
      }
    }
}

// ---------------- BN stats: per-channel sum/sumsq over M=16384 ----------------
__global__ void k_stats(const float* __restrict__ acc, float* __restrict__ sum,
                        float* __restrict__ sq){
  const int m0 = blockIdx.x*64;
  const int c = threadIdx.x;
  float s = 0.f, q = 0.f;
  for(int i=0;i<64;i++){
    float v = acc[(size_t)(m0+i)*256 + c];
    s += v; q += v*v;
  }
  unsafeAtomicAdd(sum + c, s);
  unsafeAtomicAdd(sq + c, q);
}

// ---------------- BN1 + ReLU -> bf16 NHWC ----------------
__global__ void k_bn1(const float* __restrict__ acc, const float* __restrict__ sum,
                      const float* __restrict__ sq, const float* __restrict__ g,
                      const float* __restrict__ bt, u16* __restrict__ o){
  __shared__ float sc[256], sh[256];
  const int t = threadIdx.x;
  {
    float mean = sum[t] * (1.f/16384.f);
    float var  = sq[t] * (1.f/16384.f) - mean*mean;
    float rstd = rsqrtf(var + 1e-5f);
    float s = g[t] * rstd;
    sc[t] = s; sh[t] = bt[t] - mean*s;
  }
  __syncthreads();
  const int c4 = (t & 63) * 4;
  const float s0 = sc[c4], s1 = sc[c4+1], s2 = sc[c4+2], s3 = sc[c4+3];
  const float h0 = sh[c4], h1 = sh[c4+1], h2 = sh[c4+2], h3 = sh[c4+3];
#pragma unroll
  for(int k=0;k<4;k++){
    int m = blockIdx.x*16 + k*4 + (t>>6);
    const float4 v = *(const float4*)(acc + (size_t)m*256 + c4);
    unsigned int lo = (unsigned int)(u16)f2bf(fmaxf(0.f, v.x*s0 + h0))
                    | ((unsigned int)(u16)f2bf(fmaxf(0.f, v.y*s1 + h1)) << 16);
    unsigned int hi = (unsigned int)(u16)f2bf(fmaxf(0.f, v.z*s2 + h2))
                    | ((unsigned int)(u16)f2bf(fmaxf(0.f, v.w*s3 + h3)) << 16);
    uint2 pr; pr.x = lo; pr.y = hi;
    *(uint2*)(o + (size_t)m*256 + c4) = pr;
  }
}

// ---------------- BN2 + ReLU + NHWC->NCHW fp32 output ----------------
__global__ void k_bn2_out(const float* __restrict__ acc, const float* __restrict__ sum,
                          const float* __restrict__ sq, const float* __restrict__ g,
                          const float* __restrict__ bt, float* __restrict__ out){
  __shared__ float tile[64][65];
  __shared__ float sc[64], sh[64];
  const int t = threadIdx.x;
  const int b = blockIdx.z, c0 = blockIdx.y*64, hw0 = blockIdx.x*64;
  if(t < 64){
    int c = c0 + t;
    float mean = sum[c] * (1.f/16384.f);
    float var  = sq[c] * (1.f/16384.f) - mean*mean;
    float rstd = rsqrtf(var + 1e-5f);
    float s = g[c] * rstd;
    sc[t] = s; sh[t] = bt[c] - mean*s;
  }
  __syncthreads();
#pragma unroll
  for(int k=0;k<16;k++){
    int idx = t + k*256;
    int wl = idx >> 6, cl = idx & 63;
    float v = acc[(size_t)((b<<12) + hw0 + wl)*256 + c0 + cl];
    tile[wl][cl] = fmaxf(0.f, v*sc[cl] + sh[cl]);
  }
  __syncthreads();
#pragma unroll
  for(int k=0;k<16;k++){
    int idx = t + k*256;
    int cl = idx >> 6, wl = idx & 63;
    out[(size_t)(b*256 + c0 + cl)*4096 + hw0 + wl] = tile[wl][cl];
  }
}

extern "C" void kernel_launch(void* const* d_in, const int* in_sizes, int n_in,
                              void* d_out, int out_size, void* d_ws, size_t ws_size,
                              hipStream_t stream){
  const float* in_v  = (const float*)d_in[0];
  const float* in_i  = (const float*)d_in[1];
  const float* w_off = (const float*)d_in[2];
  const float* b_off = (const float*)d_in[3];
  const float* w_dcn = (const float*)d_in[4];
  const float* g1    = (const float*)d_in[5];
  const float* bt1   = (const float*)d_in[6];
  const float* w2    = (const float*)d_in[7];
  const float* g2    = (const float*)d_in[8];
  const float* bt2   = (const float*)d_in[9];
  float* out = (float*)d_out;
  char* ws = (char*)d_ws;

  float* off_acc  = (float*)(ws + OFF_ACC_B);
  float* out1_acc = (float*)(ws + OUT1_ACC_B);
  float* out2_acc = (float*)(ws + OUT2_ACC_B);
  float* stats    = (float*)(ws + STATS_B);
  float* sum1 = stats,       *sq1 = stats + 256;
  float* sum2 = stats + 512, *sq2 = stats + 768;
  u16* xn    = (u16*)(ws + XN_B);
  u16* out1n = (u16*)(ws + OUT1N_B);
  u16* wofft = (u16*)(ws + WOFFT_B);
  u16* wdcnt = (u16*)(ws + WDCNT_B);
  u16* w2t   = (u16*)(ws + W2T_B);

  hipMemsetAsync(ws, 0, ZERO_BYTES, stream);
  k_x_to_nhwc<<<dim3(64,8,4), 256, 0, stream>>>(in_v, in_i, xn);
  k_prep_woff<<<576, 256, 0, stream>>>(w_off, wofft);
  k_prep_wdcn<<<4608, 256, 0, stream>>>(w_dcn, wdcnt);
  k_prep_w2<<<2304, 256, 0, stream>>>(w2, w2t);
  k_conv_off<<<dim3(128,4), 256, 0, stream>>>(xn, wofft, off_acc);
  k_dcn<<<dim3(256,2), 256, 0, stream>>>(xn, wdcnt, off_acc, b_off, out1_acc);
  k_stats<<<256, 256, 0, stream>>>(out1_acc, sum1, sq1);
  k_bn1<<<1024, 256, 0, stream>>>(out1_acc, sum1, sq1, g1, bt1, out1n);
  k_conv2<<<dim3(256,2), 256, 0, stream>>>(out1n, w2t, out2_acc);
  k_stats<<<256, 256, 0, stream>>>(out2_acc, sum2, sq2);
  k_bn2_out<<<dim3(64,4,4), 256, 0, stream>>>(out2_acc, sum2, sq2, g2, bt2, out);
}

// Round 3
// 352.002 us; speedup vs baseline: 1.1277x; 1.0018x over previous
//
#include <hip/hip_runtime.h>
#include <cstdint>
#include <cstddef>

typedef unsigned short u16;
typedef __attribute__((ext_vector_type(8))) short s16x8;
typedef __attribute__((ext_vector_type(4))) float f32x4;

#define DEV __device__ __forceinline__

DEV float bf2f(short u){
  union { unsigned int i; float f; } v;
  v.i = ((unsigned int)(u16)u) << 16;
  return v.f;
}
DEV short f2bf(float f){
  union { float f; unsigned int i; } v; v.f = f;
  unsigned int u = v.i;
  u += 0x7fffu + ((u >> 16) & 1u);   // RNE
  return (short)(u >> 16);
}
DEV s16x8 s16x8_zero(){
  s16x8 z;
#pragma unroll
  for(int j=0;j<8;j++) z[j]=0;
  return z;
}
DEV f32x4 f32x4_zero(){
  f32x4 z;
#pragma unroll
  for(int j=0;j<4;j++) z[j]=0.f;
  return z;
}
DEV f32x4 mfma16(s16x8 a, s16x8 b, f32x4 c){
  return __builtin_amdgcn_mfma_f32_16x16x32_bf16(a, b, c, 0, 0, 0);
}
// Raw barrier WITHOUT the frontend's vmcnt(0) drain: LDS ops drained (both our
// reads finishing and our writes becoming visible), but global prefetches stay
// in flight across the barrier (T3/T4 pattern; __syncthreads() would kill them).
DEV void bar_lds(){
  asm volatile("s_waitcnt lgkmcnt(0)");
  __builtin_amdgcn_s_barrier();
}

// ---------------- problem constants ----------------
// B=4, Cin=512 (concat), H=W=64, P=9 taps, Cout=256, M = B*H*W = 16384
// workspace layout (bytes), all 256B-aligned
static constexpr size_t OFF_ACC_B  = 0;                        // float[16384*32]
static constexpr size_t OUT1_ACC_B = 2097152;                  // float[16384*256]
static constexpr size_t OUT2_ACC_B = OUT1_ACC_B + 16777216;    // float[16384*256]
static constexpr size_t STATS_B    = OUT2_ACC_B + 16777216;    // float[1024]
static constexpr size_t ZERO_BYTES = STATS_B + 4096;
static constexpr size_t XN_B       = ZERO_BYTES;               // u16[16384*512]
static constexpr size_t OUT1N_B    = XN_B + 16777216;          // u16[16384*256]
static constexpr size_t WOFFT_B    = OUT1N_B + 8388608;        // u16[32*4608]
static constexpr size_t WDCNT_B    = WOFFT_B + 294912;         // u16[256*4608]
static constexpr size_t W2T_B      = WDCNT_B + 2359296;        // u16[256*2304]
// total ~61.7 MB

// ---------------- NCHW fp32 (concat) -> NHWC bf16 ----------------
__global__ void k_x_to_nhwc(const float* __restrict__ v, const float* __restrict__ vi,
                            u16* __restrict__ xn){
  __shared__ float tile[64][65];
  const int b = blockIdx.z, c0 = blockIdx.y*64, hw0 = blockIdx.x*64;
  const float* src = (c0 < 256) ? (v  + ((size_t)b*256 + c0)      *4096)
                                : (vi + ((size_t)b*256 + (c0-256))*4096);
  const int t = threadIdx.x;
#pragma unroll
  for(int k=0;k<16;k++){
    int idx = t + k*256;
    int cl = idx >> 6, wl = idx & 63;
    tile[cl][wl] = src[(size_t)cl*4096 + hw0 + wl];
  }
  __syncthreads();
#pragma unroll
  for(int k=0;k<16;k++){
    int idx = t + k*256;
    int wl = idx >> 6, cl = idx & 63;
    xn[(size_t)(b*4096 + hw0 + wl)*512 + c0 + cl] = (u16)f2bf(tile[cl][wl]);
  }
}

// ---------------- weight repacks: OIHW fp32 -> [N][K] bf16, K = tap*C + c ----------------
__global__ void k_prep_woff(const float* __restrict__ w, u16* __restrict__ wt){
  int idx = blockIdx.x*256 + threadIdx.x;
  if(idx >= 32*4608) return;
  int n = idx / 4608, k = idx % 4608;
  int t = k >> 9, c = k & 511;
  float val = (n < 27) ? w[(size_t)(n*512 + c)*9 + t] : 0.f;
  wt[idx] = (u16)f2bf(val);
}
__global__ void k_prep_wdcn(const float* __restrict__ w, u16* __restrict__ wt){
  int idx = blockIdx.x*256 + threadIdx.x;
  if(idx >= 256*4608) return;
  int n = idx / 4608, k = idx % 4608;
  int t = k >> 9, c = k & 511;
  wt[idx] = (u16)f2bf(w[(size_t)(n*512 + c)*9 + t]);
}
__global__ void k_prep_w2(const float* __restrict__ w, u16* __restrict__ wt){
  int idx = blockIdx.x*256 + threadIdx.x;
  if(idx >= 256*2304) return;
  int n = idx / 2304, k = idx % 2304;
  int t = k >> 8, c = k & 255;
  wt[idx] = (u16)f2bf(w[(size_t)(n*256 + c)*9 + t]);
}

// ---------------- offset conv: 512ch -> 27(pad 32), implicit GEMM ----------------
// grid (128 m-tiles of 128, 4 k-splits by taps {0,2}{2,4}{4,6}{6,9}); depth-2 prefetch
__global__ __launch_bounds__(256, 2) void k_conv_off(
    const u16* __restrict__ xn, const u16* __restrict__ wt, float* __restrict__ offa){
  __shared__ short A_lds[4][128][8];   // [k/8][row][8]
  __shared__ short B_lds[4][32][8];
  const int tid = threadIdx.x;
  const int lane = tid & 63, wid = tid >> 6;
  const int quad = lane >> 4, ln = lane & 15;
  const int m0 = blockIdx.x * 128;
  const int b = m0 >> 12;
  const int h0 = (m0 & 4095) >> 6;
  const int ks = blockIdx.y;
  const int ts0 = (ks == 3) ? 6 : ks*2;
  const int ntap = (ks == 3) ? 3 : 2;
  const int m_base = wid * 32;
  const int r = tid >> 1, sp = (tid & 1) * 2;
  const int h_r = h0 + (r >> 6), w_r = r & 63;
  const s16x8* Ap = (const s16x8*)A_lds;
  const s16x8* Bp = (const s16x8*)B_lds;
  f32x4 acc[2][2];
#pragma unroll
  for(int mf=0;mf<2;mf++)
#pragma unroll
    for(int nf=0;nf<2;nf++) acc[mf][nf] = f32x4_zero();

  auto load_it = [&](int it, s16x8& v0, s16x8& v1, s16x8& bv){
    const int tp = ts0 + (it >> 4);
    const int cA = (it & 15)*32;
    const int ty = tp/3, tx = tp - ty*3;
    const int y = h_r - 1 + ty, x = w_r - 1 + tx;
    const bool vld = (y>=0) & (y<64) & (x>=0) & (x<64);
    v0 = s16x8_zero(); v1 = s16x8_zero();
    if(vld){
      const u16* src = xn + ((size_t)((b<<12) + (y<<6) + x) << 9) + cA + sp*8;
      v0 = *(const s16x8*)(src);
      v1 = *(const s16x8*)(src + 8);
    }
    if(tid < 128){
      const int n = tid & 31, s2 = tid >> 5;
      bv = *(const s16x8*)(wt + (size_t)n*4608 + tp*512 + cA + s2*8);
    }
  };

  const int NIT = ntap * 16;      // 32 or 48 (always even)
  s16x8 v0a, v1a, bva, v0b, v1b, bvb;
  bva = s16x8_zero(); bvb = s16x8_zero();
  load_it(0, v0a, v1a, bva);
  load_it(1, v0b, v1b, bvb);
  for(int it = 0; it < NIT; it += 2){
    // ---- even sub-iter: consume set A, prefetch it+2 into set A
    bar_lds();
    *(s16x8*)(&A_lds[sp][r][0])   = v0a;
    *(s16x8*)(&A_lds[sp+1][r][0]) = v1a;
    if(tid < 128){
      const int n = tid & 31, s2 = tid >> 5;
      *(s16x8*)(&B_lds[s2][n][0]) = bva;
    }
    if(it + 2 < NIT) load_it(it + 2, v0a, v1a, bva);
    bar_lds();
    {
      s16x8 a0 = Ap[quad*128 + m_base + ln];
      s16x8 a1 = Ap[quad*128 + m_base + 16 + ln];
      s16x8 b0 = Bp[quad*32 + ln];
      s16x8 b1 = Bp[quad*32 + 16 + ln];
      acc[0][0] = mfma16(a0, b0, acc[0][0]);
      acc[0][1] = mfma16(a0, b1, acc[0][1]);
      acc[1][0] = mfma16(a1, b0, acc[1][0]);
      acc[1][1] = mfma16(a1, b1, acc[1][1]);
    }
    // ---- odd sub-iter: consume set B, prefetch it+3 into set B
    bar_lds();
    *(s16x8*)(&A_lds[sp][r][0])   = v0b;
    *(s16x8*)(&A_lds[sp+1][r][0]) = v1b;
    if(tid < 128){
      const int n = tid & 31, s2 = tid >> 5;
      *(s16x8*)(&B_lds[s2][n][0]) = bvb;
    }
    if(it + 3 < NIT) load_it(it + 3, v0b, v1b, bvb);
    bar_lds();
    {
      s16x8 a0 = Ap[quad*128 + m_base + ln];
      s16x8 a1 = Ap[quad*128 + m_base + 16 + ln];
      s16x8 b0 = Bp[quad*32 + ln];
      s16x8 b1 = Bp[quad*32 + 16 + ln];
      acc[0][0] = mfma16(a0, b0, acc[0][0]);
      acc[0][1] = mfma16(a0, b1, acc[0][1]);
      acc[1][0] = mfma16(a1, b0, acc[1][0]);
      acc[1][1] = mfma16(a1, b1, acc[1][1]);
    }
  }
#pragma unroll
  for(int mf=0;mf<2;mf++)
#pragma unroll
    for(int nf=0;nf<2;nf++){
      const int col = nf*16 + ln;
#pragma unroll
      for(int i=0;i<4;i++){
        const int row = m_base + mf*16 + quad*4 + i;
        unsafeAtomicAdd(offa + (size_t)(m0+row)*32 + col, acc[mf][nf][i]);
      }
    }
}

// ---------------- DCN main: bilinear-sample A rows, GEMM vs w_dcn ----------------
// grid (256 m-tiles of 64, 2 k-splits by taps {0..3},{4..8}); depth-2 prefetch
__global__ __launch_bounds__(256, 2) void k_dcn(
    const u16* __restrict__ xn, const u16* __restrict__ wt,
    const float* __restrict__ offa, const float* __restrict__ boff,
    float* __restrict__ outa){
  __shared__ short A_lds[4][64][8];
  __shared__ short B_lds[4][256][8];
  __shared__ int   p_ofs[5][4][64];
  __shared__ float p_wgt[5][4][64];
  const int tid = threadIdx.x;
  const int lane = tid & 63, wid = tid >> 6;
  const int quad = lane >> 4, ln = lane & 15;
  const int m0 = blockIdx.x * 64;
  const int b = m0 >> 12;
  const int h = (m0 & 4095) >> 6;
  const int tg = blockIdx.y;
  const int ts0 = tg ? 4 : 0;
  const int ntap = tg ? 5 : 4;
  const int wm = wid >> 1, wn = wid & 1;
  const int m_base = wm*32, n_base = wn*128;
  const int r = tid >> 2, sub = tid & 3;
  const s16x8* Ap = (const s16x8*)A_lds;
  const s16x8* Bp = (const s16x8*)B_lds;
  const u16* wrowt = wt + (size_t)tid*4608;
  f32x4 acc[2][8];
#pragma unroll
  for(int mf=0;mf<2;mf++)
#pragma unroll
    for(int nf=0;nf<8;nf++) acc[mf][nf] = f32x4_zero();

  // ---- one-time: bilinear offsets/weights for ALL taps of this block ----
  {
    const int rr = tid & 63;
    const float* orow = offa + (size_t)(m0+rr)*32;
    for(int tpi = tid >> 6; tpi < ntap; tpi += 4){
      const int tp = ts0 + tpi;
      float dy = orow[2*tp]   + boff[2*tp];
      float dx = orow[2*tp+1] + boff[2*tp+1];
      float mz = orow[18+tp]  + boff[18+tp];
      float mk = 1.f / (1.f + expf(-mz));               // modulation mask
      float ypos = (float)(h - 1 + tp/3) + dy;
      float xpos = (float)(rr - 1 + tp%3) + dx;
      float y0f = floorf(ypos), x0f = floorf(xpos);
      float ly = ypos - y0f, lx = xpos - x0f;
      int y0 = (int)y0f, x0 = (int)x0f;
#pragma unroll
      for(int k=0;k<4;k++){
        int ddy = k >> 1, ddx = k & 1;
        int yi = y0 + ddy, xi = x0 + ddx;
        bool vv = (yi >= 0) & (yi < 64) & (xi >= 0) & (xi < 64);
        float wk = (ddy ? ly : 1.f-ly) * (ddx ? lx : 1.f-lx) * mk;
        if(!vv) wk = 0.f;
        int yc = yi < 0 ? 0 : (yi > 63 ? 63 : yi);
        int xc = xi < 0 ? 0 : (xi > 63 ? 63 : xi);
        p_ofs[tpi][k][rr] = ((b << 12) + (yc << 6) + xc) << 9;  // *512 channels
        p_wgt[tpi][k][rr] = wk;
      }
    }
  }
  __syncthreads();

  auto loadA = [&](int it, s16x8& a0, s16x8& a1, s16x8& a2, s16x8& a3,
                   float& w0, float& w1, float& w2, float& w3){
    const int tpi = it >> 4;
    const int c0 = (it & 15)*32 + sub*8;
    w0 = p_wgt[tpi][0][r]; w1 = p_wgt[tpi][1][r];
    w2 = p_wgt[tpi][2][r]; w3 = p_wgt[tpi][3][r];
    a0 = *(const s16x8*)(xn + p_ofs[tpi][0][r] + c0);
    a1 = *(const s16x8*)(xn + p_ofs[tpi][1][r] + c0);
    a2 = *(const s16x8*)(xn + p_ofs[tpi][2][r] + c0);
    a3 = *(const s16x8*)(xn + p_ofs[tpi][3][r] + c0);
  };
  auto loadB = [&](int it, s16x8& b0, s16x8& b1, s16x8& b2, s16x8& b3){
    const int kb = (ts0 + (it >> 4))*512 + (it & 15)*32;
    b0 = *(const s16x8*)(wrowt + kb);
    b1 = *(const s16x8*)(wrowt + kb + 8);
    b2 = *(const s16x8*)(wrowt + kb + 16);
    b3 = *(const s16x8*)(wrowt + kb + 24);
  };
  auto blend = [&](const s16x8& a0, const s16x8& a1, const s16x8& a2, const s16x8& a3,
                   float w0, float w1, float w2, float w3){
    s16x8 pk;
#pragma unroll
    for(int j=0;j<8;j++){
      float f = w0 * bf2f(a0[j]);
      f = fmaf(w1, bf2f(a1[j]), f);
      f = fmaf(w2, bf2f(a2[j]), f);
      f = fmaf(w3, bf2f(a3[j]), f);
      pk[j] = f2bf(f);
    }
    return pk;
  };

  const int NIT = ntap * 16;   // 64 or 80 (always even)
  s16x8 aA0,aA1,aA2,aA3, bA0,bA1,bA2,bA3;
  s16x8 aB0,aB1,aB2,aB3, bB0,bB1,bB2,bB3;
  float wA0,wA1,wA2,wA3, wB0,wB1,wB2,wB3;
  loadA(0, aA0,aA1,aA2,aA3, wA0,wA1,wA2,wA3);
  loadB(0, bA0,bA1,bA2,bA3);
  loadA(1, aB0,aB1,aB2,aB3, wB0,wB1,wB2,wB3);
  loadB(1, bB0,bB1,bB2,bB3);

  for(int it = 0; it < NIT; it += 2){
    // ---- even sub-iter: set A
    {
      s16x8 pk = blend(aA0,aA1,aA2,aA3, wA0,wA1,wA2,wA3);
      if(it + 2 < NIT) loadA(it + 2, aA0,aA1,aA2,aA3, wA0,wA1,wA2,wA3);
      bar_lds();
      *(s16x8*)(&A_lds[sub][r][0]) = pk;
      *(s16x8*)(&B_lds[0][tid][0]) = bA0;
      *(s16x8*)(&B_lds[1][tid][0]) = bA1;
      *(s16x8*)(&B_lds[2][tid][0]) = bA2;
      *(s16x8*)(&B_lds[3][tid][0]) = bA3;
      if(it + 2 < NIT) loadB(it + 2, bA0,bA1,bA2,bA3);
      bar_lds();
      s16x8 af0 = Ap[quad*64 + m_base + ln];
      s16x8 af1 = Ap[quad*64 + m_base + 16 + ln];
      s16x8 bfr[8];
#pragma unroll
      for(int nf=0;nf<8;nf++) bfr[nf] = Bp[quad*256 + n_base + nf*16 + ln];
#pragma unroll
      for(int nf=0;nf<8;nf++){
        acc[0][nf] = mfma16(af0, bfr[nf], acc[0][nf]);
        acc[1][nf] = mfma16(af1, bfr[nf], acc[1][nf]);
      }
    }
    // ---- odd sub-iter: set B
    {
      s16x8 pk = blend(aB0,aB1,aB2,aB3, wB0,wB1,wB2,wB3);
      if(it + 3 < NIT) loadA(it + 3, aB0,aB1,aB2,aB3, wB0,wB1,wB2,wB3);
      bar_lds();
      *(s16x8*)(&A_lds[sub][r][0]) = pk;
      *(s16x8*)(&B_lds[0][tid][0]) = bB0;
      *(s16x8*)(&B_lds[1][tid][0]) = bB1;
      *(s16x8*)(&B_lds[2][tid][0]) = bB2;
      *(s16x8*)(&B_lds[3][tid][0]) = bB3;
      if(it + 3 < NIT) loadB(it + 3, bB0,bB1,bB2,bB3);
      bar_lds();
      s16x8 af0 = Ap[quad*64 + m_base + ln];
      s16x8 af1 = Ap[quad*64 + m_base + 16 + ln];
      s16x8 bfr[8];
#pragma unroll
      for(int nf=0;nf<8;nf++) bfr[nf] = Bp[quad*256 + n_base + nf*16 + ln];
#pragma unroll
      for(int nf=0;nf<8;nf++){
        acc[0][nf] = mfma16(af0, bfr[nf], acc[0][nf]);
        acc[1][nf] = mfma16(af1, bfr[nf], acc[1][nf]);
      }
    }
  }
#pragma unroll
  for(int mf=0;mf<2;mf++)
#pragma unroll
    for(int nf=0;nf<8;nf++){
      const int col = n_base + nf*16 + ln;
#pragma unroll
      for(int i=0;i<4;i++){
        const int row = m_base + mf*16 + quad*4 + i;
        unsafeAtomicAdd(outa + (size_t)(m0+row)*256 + col, acc[mf][nf][i]);
      }
    }
}

// ---------------- conv2: 256 -> 256, implicit GEMM on normalized out1 ----------------
// grid (256 m-tiles of 64, 2 k-splits by taps {0..3},{4..8}); depth-2 prefetch
__global__ __launch_bounds__(256, 2) void k_conv2(
    const u16* __restrict__ a_in, const u16* __restrict__ wt, float* __restrict__ outa){
  __shared__ short A_lds[4][64][8];
  __shared__ short B_lds[4][256][8];
  const int tid = threadIdx.x;
  const int lane = tid & 63, wid = tid >> 6;
  const int quad = lane >> 4, ln = lane & 15;
  const int m0 = blockIdx.x * 64;
  const int b = m0 >> 12;
  const int h = (m0 & 4095) >> 6;
  const int tg = blockIdx.y;
  const int ts0 = tg ? 4 : 0;
  const int ntap = tg ? 5 : 4;
  const int wm = wid >> 1, wn = wid & 1;
  const int m_base = wm*32, n_base = wn*128;
  const int r = tid >> 2, sub = tid & 3;
  const s16x8* Ap = (const s16x8*)A_lds;
  const s16x8* Bp = (const s16x8*)B_lds;
  const u16* wrowt = wt + (size_t)tid*2304;
  f32x4 acc[2][8];
#pragma unroll
  for(int mf=0;mf<2;mf++)
#pragma unroll
    for(int nf=0;nf<8;nf++) acc[mf][nf] = f32x4_zero();

  auto load_it = [&](int it, s16x8& va, s16x8& b0, s16x8& b1, s16x8& b2, s16x8& b3){
    const int tp = ts0 + (it >> 3);
    const int c0 = (it & 7)*32;
    const int ty = tp/3, tx = tp - ty*3;
    const int y = h - 1 + ty, x = r - 1 + tx;
    const bool vld = (y>=0) & (y<64) & (x>=0) & (x<64);
    va = s16x8_zero();
    if(vld) va = *(const s16x8*)(a_in + (((size_t)((b<<12) + (y<<6) + x)) << 8) + c0 + sub*8);
    const int kb = tp*256 + c0;
    b0 = *(const s16x8*)(wrowt + kb);
    b1 = *(const s16x8*)(wrowt + kb + 8);
    b2 = *(const s16x8*)(wrowt + kb + 16);
    b3 = *(const s16x8*)(wrowt + kb + 24);
  };

  const int NIT = ntap * 8;    // 32 or 40 (always even)
  s16x8 vA, bA0,bA1,bA2,bA3;
  s16x8 vB, bB0,bB1,bB2,bB3;
  load_it(0, vA, bA0,bA1,bA2,bA3);
  load_it(1, vB, bB0,bB1,bB2,bB3);
  for(int it = 0; it < NIT; it += 2){
    // ---- even sub-iter: set A
    bar_lds();
    *(s16x8*)(&A_lds[sub][r][0]) = vA;
    *(s16x8*)(&B_lds[0][tid][0]) = bA0;
    *(s16x8*)(&B_lds[1][tid][0]) = bA1;
    *(s16x8*)(&B_lds[2][tid][0]) = bA2;
    *(s16x8*)(&B_lds[3][tid][0]) = bA3;
    if(it + 2 < NIT) load_it(it + 2, vA, bA0,bA1,bA2,bA3);
    bar_lds();
    {
      s16x8 af0 = Ap[quad*64 + m_base + ln];
      s16x8 af1 = Ap[quad*64 + m_base + 16 + ln];
      s16x8 bfr[8];
#pragma unroll
      for(int nf=0;nf<8;nf++) bfr[nf] = Bp[quad*256 + n_base + nf*16 + ln];
#pragma unroll
      for(int nf=0;nf<8;nf++){
        acc[0][nf] = mfma16(af0, bfr[nf], acc[0][nf]);
        acc[1][nf] = mfma16(af1, bfr[nf], acc[1][nf]);
      }
    }
    // ---- odd sub-iter: set B
    bar_lds();
    *(s16x8*)(&A_lds[sub][r][0]) = vB;
    *(s16x8*)(&B_lds[0][tid][0]) = bB0;
    *(s16x8*)(&B_lds[1][tid][0]) = bB1;
    *(s16x8*)(&B_lds[2][tid][0]) = bB2;
    *(s16x8*)(&B_lds[3][tid][0]) = bB3;
    if(it + 3 < NIT) load_it(it + 3, vB, bB0,bB1,bB2,bB3);
    bar_lds();
    {
      s16x8 af0 = Ap[quad*64 + m_base + ln];
      s16x8 af1 = Ap[quad*64 + m_base + 16 + ln];
      s16x8 bfr[8];
#pragma unroll
      for(int nf=0;nf<8;nf++) bfr[nf] = Bp[quad*256 + n_base + nf*16 + ln];
#pragma unroll
      for(int nf=0;nf<8;nf++){
        acc[0][nf] = mfma16(af0, bfr[nf], acc[0][nf]);
        acc[1][nf] = mfma16(af1, bfr[nf], acc[1][nf]);
      }
    }
  }
#pragma unroll
  for(int mf=0;mf<2;mf++)
#pragma unroll
    for(int nf=0;nf<8;nf++){
      const int col = n_base + nf*16 + ln;
#pragma unroll
      for(int i=0;i<4;i++){
        const int row = m_base + mf*16 + quad*4 + i;
        unsafeAtomicAdd(outa + (size_t)(m0+row)*256 + col, acc[mf][nf][i]);
      }
    }
}

// ---------------- BN stats: per-channel sum/sumsq over M=16384 ----------------
__global__ void k_stats(const float* __restrict__ acc, float* __restrict__ sum,
                        float* __restrict__ sq){
  const int m0 = blockIdx.x*64;
  const int c = threadIdx.x;
  float s = 0.f, q = 0.f;
  for(int i=0;i<64;i++){
    float v = acc[(size_t)(m0+i)*256 + c];
    s += v; q += v*v;
  }
  unsafeAtomicAdd(sum + c, s);
  unsafeAtomicAdd(sq + c, q);
}

// ---------------- BN1 + ReLU -> bf16 NHWC ----------------
__global__ void k_bn1(const float* __restrict__ acc, const float* __restrict__ sum,
                      const float* __restrict__ sq, const float* __restrict__ g,
                      const float* __restrict__ bt, u16* __restrict__ o){
  __shared__ float sc[256], sh[256];
  const int t = threadIdx.x;
  {
    float mean = sum[t] * (1.f/16384.f);
    float var  = sq[t] * (1.f/16384.f) - mean*mean;
    float rstd = rsqrtf(var + 1e-5f);
    float s = g[t] * rstd;
    sc[t] = s; sh[t] = bt[t] - mean*s;
  }
  __syncthreads();
  const int c4 = (t & 63) * 4;
  const float s0 = sc[c4], s1 = sc[c4+1], s2 = sc[c4+2], s3 = sc[c4+3];
  const float h0 = sh[c4], h1 = sh[c4+1], h2 = sh[c4+2], h3 = sh[c4+3];
#pragma unroll
  for(int k=0;k<4;k++){
    int m = blockIdx.x*16 + k*4 + (t>>6);
    const float4 v = *(const float4*)(acc + (size_t)m*256 + c4);
    unsigned int lo = (unsigned int)(u16)f2bf(fmaxf(0.f, v.x*s0 + h0))
                    | ((unsigned int)(u16)f2bf(fmaxf(0.f, v.y*s1 + h1)) << 16);
    unsigned int hi = (unsigned int)(u16)f2bf(fmaxf(0.f, v.z*s2 + h2))
                    | ((unsigned int)(u16)f2bf(fmaxf(0.f, v.w*s3 + h3)) << 16);
    uint2 pr; pr.x = lo; pr.y = hi;
    *(uint2*)(o + (size_t)m*256 + c4) = pr;
  }
}

// ---------------- BN2 + ReLU + NHWC->NCHW fp32 output ----------------
__global__ void k_bn2_out(const float* __restrict__ acc, const float* __restrict__ sum,
                          const float* __restrict__ sq, const float* __restrict__ g,
                          const float* __restrict__ bt, float* __restrict__ out){
  __shared__ float tile[64][65];
  __shared__ float sc[64], sh[64];
  const int t = threadIdx.x;
  const int b = blockIdx.z, c0 = blockIdx.y*64, hw0 = blockIdx.x*64;
  if(t < 64){
    int c = c0 + t;
    float mean = sum[c] * (1.f/16384.f);
    float var  = sq[c] * (1.f/16384.f) - mean*mean;
    float rstd = rsqrtf(var + 1e-5f);
    float s = g[c] * rstd;
    sc[t] = s; sh[t] = bt[c] - mean*s;
  }
  __syncthreads();
#pragma unroll
  for(int k=0;k<16;k++){
    int idx = t + k*256;
    int wl = idx >> 6, cl = idx & 63;
    float v = acc[(size_t)((b<<12) + hw0 + wl)*256 + c0 + cl];
    tile[wl][cl] = fmaxf(0.f, v*sc[cl] + sh[cl]);
  }
  __syncthreads();
#pragma unroll
  for(int k=0;k<16;k++){
    int idx = t + k*256;
    int cl = idx >> 6, wl = idx & 63;
    out[(size_t)(b*256 + c0 + cl)*4096 + hw0 + wl] = tile[wl][cl];
  }
}

extern "C" void kernel_launch(void* const* d_in, const int* in_sizes, int n_in,
                              void* d_out, int out_size, void* d_ws, size_t ws_size,
                              hipStream_t stream){
  const float* in_v  = (const float*)d_in[0];
  const float* in_i  = (const float*)d_in[1];
  const float* w_off = (const float*)d_in[2];
  const float* b_off = (const float*)d_in[3];
  const float* w_dcn = (const float*)d_in[4];
  const float* g1    = (const float*)d_in[5];
  const float* bt1   = (const float*)d_in[6];
  const float* w2    = (const float*)d_in[7];
  const float* g2    = (const float*)d_in[8];
  const float* bt2   = (const float*)d_in[9];
  float* out = (float*)d_out;
  char* ws = (char*)d_ws;

  float* off_acc  = (float*)(ws + OFF_ACC_B);
  float* out1_acc = (float*)(ws + OUT1_ACC_B);
  float* out2_acc = (float*)(ws + OUT2_ACC_B);
  float* stats    = (float*)(ws + STATS_B);
  float* sum1 = stats,       *sq1 = stats + 256;
  float* sum2 = stats + 512, *sq2 = stats + 768;
  u16* xn    = (u16*)(ws + XN_B);
  u16* out1n = (u16*)(ws + OUT1N_B);
  u16* wofft = (u16*)(ws + WOFFT_B);
  u16* wdcnt = (u16*)(ws + WDCNT_B);
  u16* w2t   = (u16*)(ws + W2T_B);

  hipMemsetAsync(ws, 0, ZERO_BYTES, stream);
  k_x_to_nhwc<<<dim3(64,8,4), 256, 0, stream>>>(in_v, in_i, xn);
  k_prep_woff<<<576, 256, 0, stream>>>(w_off, wofft);
  k_prep_wdcn<<<4608, 256, 0, stream>>>(w_dcn, wdcnt);
  k_prep_w2<<<2304, 256, 0, stream>>>(w2, w2t);
  k_conv_off<<<dim3(128,4), 256, 0, stream>>>(xn, wofft, off_acc);
  k_dcn<<<dim3(256,2), 256, 0, stream>>>(xn, wdcnt, off_acc, b_off, out1_acc);
  k_stats<<<256, 256, 0, stream>>>(out1_acc, sum1, sq1);
  k_bn1<<<1024, 256, 0, stream>>>(out1_acc, sum1, sq1, g1, bt1, out1n);
  k_conv2<<<dim3(256,2), 256, 0, stream>>>(out1n, w2t, out2_acc);
  k_stats<<<256, 256, 0, stream>>>(out2_acc, sum2, sq2);
  k_bn2_out<<<dim3(64,4,4), 256, 0, stream>>>(out2_acc, sum2, sq2, g2, bt2, out);
}

// Round 4
// 350.306 us; speedup vs baseline: 1.1331x; 1.0048x over previous
//
#include <hip/hip_runtime.h>
#include <cstdint>
#include <cstddef>

typedef unsigned short u16;
typedef __attribute__((ext_vector_type(8))) short s16x8;
typedef __attribute__((ext_vector_type(4))) float f32x4;

#define DEV __device__ __forceinline__

DEV float bf2f(short u){
  union { unsigned int i; float f; } v;
  v.i = ((unsigned int)(u16)u) << 16;
  return v.f;
}
DEV short f2bf(float f){
  union { float f; unsigned int i; } v; v.f = f;
  unsigned int u = v.i;
  u += 0x7fffu + ((u >> 16) & 1u);   // RNE
  return (short)(u >> 16);
}
DEV s16x8 s16x8_zero(){
  s16x8 z;
#pragma unroll
  for(int j=0;j<8;j++) z[j]=0;
  return z;
}
DEV f32x4 f32x4_zero(){
  f32x4 z;
#pragma unroll
  for(int j=0;j<4;j++) z[j]=0.f;
  return z;
}
DEV f32x4 mfma16(s16x8 a, s16x8 b, f32x4 c){
  return __builtin_amdgcn_mfma_f32_16x16x32_bf16(a, b, c, 0, 0, 0);
}
// Raw barrier WITHOUT the frontend's vmcnt(0) drain: LDS ops drained, but global
// prefetches stay in flight across the barrier (T3/T4; __syncthreads() drains them).
DEV void bar_lds(){
  asm volatile("s_waitcnt lgkmcnt(0)");
  __builtin_amdgcn_s_barrier();
}

// ---------------- problem constants ----------------
// B=4, Cin=512 (concat), H=W=64, P=9 taps, Cout=256, M = B*H*W = 16384
static constexpr size_t OFF_ACC_B  = 0;                        // float[16384*32]
static constexpr size_t OUT1_ACC_B = 2097152;                  // float[16384*256]
static constexpr size_t OUT2_ACC_B = OUT1_ACC_B + 16777216;    // float[16384*256]
static constexpr size_t STATS_B    = OUT2_ACC_B + 16777216;    // float[1024]
static constexpr size_t ZERO_BYTES = STATS_B + 4096;
static constexpr size_t XN_B       = ZERO_BYTES;               // u16[16384*512]
static constexpr size_t OUT1N_B    = XN_B + 16777216;          // u16[16384*256]
static constexpr size_t WOFFT_B    = OUT1N_B + 8388608;        // u16[32*4608]
static constexpr size_t WDCNT_B    = WOFFT_B + 294912;         // u16[256*4608]
static constexpr size_t W2T_B      = WDCNT_B + 2359296;        // u16[256*2304]

// ---------------- NCHW fp32 (concat) -> NHWC bf16 ----------------
__global__ void k_x_to_nhwc(const float* __restrict__ v, const float* __restrict__ vi,
                            u16* __restrict__ xn){
  __shared__ float tile[64][65];
  const int b = blockIdx.z, c0 = blockIdx.y*64, hw0 = blockIdx.x*64;
  const float* src = (c0 < 256) ? (v  + ((size_t)b*256 + c0)      *4096)
                                : (vi + ((size_t)b*256 + (c0-256))*4096);
  const int t = threadIdx.x;
#pragma unroll
  for(int k=0;k<16;k++){
    int idx = t + k*256;
    int cl = idx >> 6, wl = idx & 63;
    tile[cl][wl] = src[(size_t)cl*4096 + hw0 + wl];
  }
  __syncthreads();
#pragma unroll
  for(int k=0;k<16;k++){
    int idx = t + k*256;
    int wl = idx >> 6, cl = idx & 63;
    xn[(size_t)(b*4096 + hw0 + wl)*512 + c0 + cl] = (u16)f2bf(tile[cl][wl]);
  }
}

// ---------------- weight repacks: OIHW fp32 -> [N][K] bf16, K = tap*C + c ----------------
__global__ void k_prep_woff(const float* __restrict__ w, u16* __restrict__ wt){
  int idx = blockIdx.x*256 + threadIdx.x;
  if(idx >= 32*4608) return;
  int n = idx / 4608, k = idx % 4608;
  int t = k >> 9, c = k & 511;
  float val = (n < 27) ? w[(size_t)(n*512 + c)*9 + t] : 0.f;
  wt[idx] = (u16)f2bf(val);
}
__global__ void k_prep_wdcn(const float* __restrict__ w, u16* __restrict__ wt){
  int idx = blockIdx.x*256 + threadIdx.x;
  if(idx >= 256*4608) return;
  int n = idx / 4608, k = idx % 4608;
  int t = k >> 9, c = k & 511;
  wt[idx] = (u16)f2bf(w[(size_t)(n*512 + c)*9 + t]);
}
__global__ void k_prep_w2(const float* __restrict__ w, u16* __restrict__ wt){
  int idx = blockIdx.x*256 + threadIdx.x;
  if(idx >= 256*2304) return;
  int n = idx / 2304, k = idx % 2304;
  int t = k >> 8, c = k & 255;
  wt[idx] = (u16)f2bf(w[(size_t)(n*256 + c)*9 + t]);
}

// ---------------- offset conv: 512ch -> 27(pad 32), implicit GEMM ----------------
// (unchanged from R3 — moderate cost; port to new structure after dcn/conv2 prove out)
__global__ __launch_bounds__(256, 2) void k_conv_off(
    const u16* __restrict__ xn, const u16* __restrict__ wt, float* __restrict__ offa){
  __shared__ short A_lds[4][128][8];
  __shared__ short B_lds[4][32][8];
  const int tid = threadIdx.x;
  const int lane = tid & 63, wid = tid >> 6;
  const int quad = lane >> 4, ln = lane & 15;
  const int m0 = blockIdx.x * 128;
  const int b = m0 >> 12;
  const int h0 = (m0 & 4095) >> 6;
  const int ks = blockIdx.y;
  const int ts0 = (ks == 3) ? 6 : ks*2;
  const int ntap = (ks == 3) ? 3 : 2;
  const int m_base = wid * 32;
  const int r = tid >> 1, sp = (tid & 1) * 2;
  const int h_r = h0 + (r >> 6), w_r = r & 63;
  const s16x8* Ap = (const s16x8*)A_lds;
  const s16x8* Bp = (const s16x8*)B_lds;
  f32x4 acc[2][2];
#pragma unroll
  for(int mf=0;mf<2;mf++)
#pragma unroll
    for(int nf=0;nf<2;nf++) acc[mf][nf] = f32x4_zero();

  auto load_it = [&](int it, s16x8& v0, s16x8& v1, s16x8& bv){
    const int tp = ts0 + (it >> 4);
    const int cA = (it & 15)*32;
    const int ty = tp/3, tx = tp - ty*3;
    const int y = h_r - 1 + ty, x = w_r - 1 + tx;
    const bool vld = (y>=0) & (y<64) & (x>=0) & (x<64);
    v0 = s16x8_zero(); v1 = s16x8_zero();
    if(vld){
      const u16* src = xn + ((size_t)((b<<12) + (y<<6) + x) << 9) + cA + sp*8;
      v0 = *(const s16x8*)(src);
      v1 = *(const s16x8*)(src + 8);
    }
    if(tid < 128){
      const int n = tid & 31, s2 = tid >> 5;
      bv = *(const s16x8*)(wt + (size_t)n*4608 + tp*512 + cA + s2*8);
    }
  };

  const int NIT = ntap * 16;
  s16x8 v0a, v1a, bva, v0b, v1b, bvb;
  bva = s16x8_zero(); bvb = s16x8_zero();
  load_it(0, v0a, v1a, bva);
  load_it(1, v0b, v1b, bvb);
  for(int it = 0; it < NIT; it += 2){
    bar_lds();
    *(s16x8*)(&A_lds[sp][r][0])   = v0a;
    *(s16x8*)(&A_lds[sp+1][r][0]) = v1a;
    if(tid < 128){
      const int n = tid & 31, s2 = tid >> 5;
      *(s16x8*)(&B_lds[s2][n][0]) = bva;
    }
    if(it + 2 < NIT) load_it(it + 2, v0a, v1a, bva);
    bar_lds();
    {
      s16x8 a0 = Ap[quad*128 + m_base + ln];
      s16x8 a1 = Ap[quad*128 + m_base + 16 + ln];
      s16x8 b0 = Bp[quad*32 + ln];
      s16x8 b1 = Bp[quad*32 + 16 + ln];
      acc[0][0] = mfma16(a0, b0, acc[0][0]);
      acc[0][1] = mfma16(a0, b1, acc[0][1]);
      acc[1][0] = mfma16(a1, b0, acc[1][0]);
      acc[1][1] = mfma16(a1, b1, acc[1][1]);
    }
    bar_lds();
    *(s16x8*)(&A_lds[sp][r][0])   = v0b;
    *(s16x8*)(&A_lds[sp+1][r][0]) = v1b;
    if(tid < 128){
      const int n = tid & 31, s2 = tid >> 5;
      *(s16x8*)(&B_lds[s2][n][0]) = bvb;
    }
    if(it + 3 < NIT) load_it(it + 3, v0b, v1b, bvb);
    bar_lds();
    {
      s16x8 a0 = Ap[quad*128 + m_base + ln];
      s16x8 a1 = Ap[quad*128 + m_base + 16 + ln];
      s16x8 b0 = Bp[quad*32 + ln];
      s16x8 b1 = Bp[quad*32 + 16 + ln];
      acc[0][0] = mfma16(a0, b0, acc[0][0]);
      acc[0][1] = mfma16(a0, b1, acc[0][1]);
      acc[1][0] = mfma16(a1, b0, acc[1][0]);
      acc[1][1] = mfma16(a1, b1, acc[1][1]);
    }
  }
#pragma unroll
  for(int mf=0;mf<2;mf++)
#pragma unroll
    for(int nf=0;nf<2;nf++){
      const int col = nf*16 + ln;
#pragma unroll
      for(int i=0;i<4;i++){
        const int row = m_base + mf*16 + quad*4 + i;
        unsafeAtomicAdd(offa + (size_t)(m0+row)*32 + col, acc[mf][nf][i]);
      }
    }
}

// ---------------- DCN main: 128x256 tile, BK=64/phase, 8 waves, depth-2 prefetch ----
// grid (128 m-tiles of 128, 2 k-splits by taps {0..3},{4..8}); 512 threads
__global__ __launch_bounds__(512, 2) void k_dcn(
    const u16* __restrict__ xn, const u16* __restrict__ wt,
    const float* __restrict__ offa, const float* __restrict__ boff,
    float* __restrict__ outa){
  __shared__ short A_lds[8][128][8];   // [ch-slice][row][8] : 16 KB
  __shared__ short B_lds[8][256][8];   // [ch-slice][n][8]  : 32 KB
  __shared__ int   p_ofs[5][4][128];   // 10 KB
  __shared__ float p_wgt[5][4][128];   // 10 KB
  const int tid = threadIdx.x;
  const int lane = tid & 63;
  const int quad = lane >> 4, ln = lane & 15;
  const int wid = tid >> 6;
  const int wm = wid >> 2, wn = wid & 3;        // 2 x 4 wave grid
  const int m0 = blockIdx.x * 128;
  const int b = m0 >> 12;
  const int h0 = (m0 & 4095) >> 6;
  const int tg = blockIdx.y;
  const int ts0 = tg ? 4 : 0;
  const int ntap = tg ? 5 : 4;
  const int r_s = tid >> 2, sub = tid & 3;      // stage map: 4 threads/row
  const int nB = tid & 255, hB = tid >> 8;      // B stage: 2 threads/n-row
  const s16x8* Ap = (const s16x8*)A_lds;
  const s16x8* Bp = (const s16x8*)B_lds;
  const u16* wrowB = wt + (size_t)nB*4608 + hB*32;
  f32x4 acc[4][4];
#pragma unroll
  for(int mf=0;mf<4;mf++)
#pragma unroll
    for(int nf=0;nf<4;nf++) acc[mf][nf] = f32x4_zero();

  // ---- one-time: bilinear offsets/weights for all taps of this block ----
  {
    const int rr = tid & 127;
    const int h_rr = h0 + (rr >> 6), w_rr = rr & 63;
    const float* orow = offa + (size_t)(m0+rr)*32;
    for(int tpi = tid >> 7; tpi < ntap; tpi += 4){
      const int tp = ts0 + tpi;
      float dy = orow[2*tp]   + boff[2*tp];
      float dx = orow[2*tp+1] + boff[2*tp+1];
      float mz = orow[18+tp]  + boff[18+tp];
      float mk = 1.f / (1.f + expf(-mz));
      float ypos = (float)(h_rr - 1 + tp/3) + dy;
      float xpos = (float)(w_rr - 1 + tp%3) + dx;
      float y0f = floorf(ypos), x0f = floorf(xpos);
      float ly = ypos - y0f, lx = xpos - x0f;
      int y0 = (int)y0f, x0 = (int)x0f;
#pragma unroll
      for(int k=0;k<4;k++){
        int ddy = k >> 1, ddx = k & 1;
        int yi = y0 + ddy, xi = x0 + ddx;
        bool vv = (yi >= 0) & (yi < 64) & (xi >= 0) & (xi < 64);
        float wk = (ddy ? ly : 1.f-ly) * (ddx ? lx : 1.f-lx) * mk;
        if(!vv) wk = 0.f;
        int yc = yi < 0 ? 0 : (yi > 63 ? 63 : yi);
        int xc = xi < 0 ? 0 : (xi > 63 ? 63 : xi);
        p_ofs[tpi][k][rr] = ((b << 12) + (yc << 6) + xc) << 9;
        p_wgt[tpi][k][rr] = wk;
      }
    }
  }
  __syncthreads();

  // per-phase: BK=64 = ch [c0, c0+64); thread stages ch slices {sub, 4+sub}
  auto loadA = [&](int p, s16x8& a00, s16x8& a01, s16x8& a10, s16x8& a11,
                   s16x8& a20, s16x8& a21, s16x8& a30, s16x8& a31,
                   float& w0, float& w1, float& w2, float& w3){
    const int tpi = p >> 3;
    const int c0 = (p & 7)*64 + sub*8;          // slice sub at c0, slice 4+sub at c0+32
    w0 = p_wgt[tpi][0][r_s]; w1 = p_wgt[tpi][1][r_s];
    w2 = p_wgt[tpi][2][r_s]; w3 = p_wgt[tpi][3][r_s];
    const u16* s0 = xn + p_ofs[tpi][0][r_s] + c0;
    const u16* s1 = xn + p_ofs[tpi][1][r_s] + c0;
    const u16* s2 = xn + p_ofs[tpi][2][r_s] + c0;
    const u16* s3 = xn + p_ofs[tpi][3][r_s] + c0;
    a00 = *(const s16x8*)(s0);  a01 = *(const s16x8*)(s0 + 32);
    a10 = *(const s16x8*)(s1);  a11 = *(const s16x8*)(s1 + 32);
    a20 = *(const s16x8*)(s2);  a21 = *(const s16x8*)(s2 + 32);
    a30 = *(const s16x8*)(s3);  a31 = *(const s16x8*)(s3 + 32);
  };
  auto loadB = [&](int p, s16x8& b0, s16x8& b1, s16x8& b2, s16x8& b3){
    const u16* src = wrowB + (ts0 + (p >> 3))*512 + (p & 7)*64;
    b0 = *(const s16x8*)(src);
    b1 = *(const s16x8*)(src + 8);
    b2 = *(const s16x8*)(src + 16);
    b3 = *(const s16x8*)(src + 24);
  };
  auto blend2 = [&](const s16x8& a0, const s16x8& a1, const s16x8& a2, const s16x8& a3,
                    float w0, float w1, float w2, float w3){
    s16x8 pk;
#pragma unroll
    for(int j=0;j<8;j++){
      float f = w0 * bf2f(a0[j]);
      f = fmaf(w1, bf2f(a1[j]), f);
      f = fmaf(w2, bf2f(a2[j]), f);
      f = fmaf(w3, bf2f(a3[j]), f);
      pk[j] = f2bf(f);
    }
    return pk;
  };
  auto mfma_phase = [&](){
#pragma unroll
    for(int kk=0;kk<2;kk++){
      s16x8 af[4], bf[4];
#pragma unroll
      for(int mf=0;mf<4;mf++) af[mf] = Ap[(kk*4+quad)*128 + wm*64 + mf*16 + ln];
#pragma unroll
      for(int nf=0;nf<4;nf++) bf[nf] = Bp[(kk*4+quad)*256 + wn*64 + nf*16 + ln];
#pragma unroll
      for(int mf=0;mf<4;mf++)
#pragma unroll
        for(int nf=0;nf<4;nf++) acc[mf][nf] = mfma16(af[mf], bf[nf], acc[mf][nf]);
    }
  };

  const int NP = ntap * 8;   // 32 or 40 (even)
  s16x8 xA00,xA01,xA10,xA11,xA20,xA21,xA30,xA31, yA00,yA01,yA10,yA11,yA20,yA21,yA30,yA31;
  s16x8 xB0,xB1,xB2,xB3, yB0,yB1,yB2,yB3;
  float xw0,xw1,xw2,xw3, yw0,yw1,yw2,yw3;
  loadA(0, xA00,xA01,xA10,xA11,xA20,xA21,xA30,xA31, xw0,xw1,xw2,xw3);
  loadB(0, xB0,xB1,xB2,xB3);
  loadA(1, yA00,yA01,yA10,yA11,yA20,yA21,yA30,yA31, yw0,yw1,yw2,yw3);
  loadB(1, yB0,yB1,yB2,yB3);

  for(int p = 0; p < NP; p += 2){
    // ---- phase p (set X)
    {
      s16x8 pk0 = blend2(xA00,xA10,xA20,xA30, xw0,xw1,xw2,xw3);
      s16x8 pk1 = blend2(xA01,xA11,xA21,xA31, xw0,xw1,xw2,xw3);
      if(p + 2 < NP) loadA(p + 2, xA00,xA01,xA10,xA11,xA20,xA21,xA30,xA31, xw0,xw1,xw2,xw3);
      bar_lds();
      *(s16x8*)(&A_lds[sub][r_s][0])     = pk0;
      *(s16x8*)(&A_lds[4+sub][r_s][0])   = pk1;
      *(s16x8*)(&B_lds[hB*4+0][nB][0]) = xB0;
      *(s16x8*)(&B_lds[hB*4+1][nB][0]) = xB1;
      *(s16x8*)(&B_lds[hB*4+2][nB][0]) = xB2;
      *(s16x8*)(&B_lds[hB*4+3][nB][0]) = xB3;
      if(p + 2 < NP) loadB(p + 2, xB0,xB1,xB2,xB3);
      bar_lds();
      mfma_phase();
    }
    // ---- phase p+1 (set Y)
    {
      s16x8 pk0 = blend2(yA00,yA10,yA20,yA30, yw0,yw1,yw2,yw3);
      s16x8 pk1 = blend2(yA01,yA11,yA21,yA31, yw0,yw1,yw2,yw3);
      if(p + 3 < NP) loadA(p + 3, yA00,yA01,yA10,yA11,yA20,yA21,yA30,yA31, yw0,yw1,yw2,yw3);
      bar_lds();
      *(s16x8*)(&A_lds[sub][r_s][0])     = pk0;
      *(s16x8*)(&A_lds[4+sub][r_s][0])   = pk1;
      *(s16x8*)(&B_lds[hB*4+0][nB][0]) = yB0;
      *(s16x8*)(&B_lds[hB*4+1][nB][0]) = yB1;
      *(s16x8*)(&B_lds[hB*4+2][nB][0]) = yB2;
      *(s16x8*)(&B_lds[hB*4+3][nB][0]) = yB3;
      if(p + 3 < NP) loadB(p + 3, yB0,yB1,yB2,yB3);
      bar_lds();
      mfma_phase();
    }
  }
#pragma unroll
  for(int mf=0;mf<4;mf++)
#pragma unroll
    for(int nf=0;nf<4;nf++){
      const int col = wn*64 + nf*16 + ln;
#pragma unroll
      for(int i=0;i<4;i++){
        const int row = wm*64 + mf*16 + quad*4 + i;
        unsafeAtomicAdd(outa + (size_t)(m0+row)*256 + col, acc[mf][nf][i]);
      }
    }
}

// ---------------- conv2: 256 -> 256, 128x256 tile, BK=64/phase, 8 waves ----------------
// grid (128 m-tiles of 128, 2 k-splits by taps {0..3},{4..8}); 512 threads
__global__ __launch_bounds__(512, 2) void k_conv2(
    const u16* __restrict__ a_in, const u16* __restrict__ wt, float* __restrict__ outa){
  __shared__ short A_lds[8][128][8];   // 16 KB
  __shared__ short B_lds[8][256][8];   // 32 KB
  const int tid = threadIdx.x;
  const int lane = tid & 63;
  const int quad = lane >> 4, ln = lane & 15;
  const int wid = tid >> 6;
  const int wm = wid >> 2, wn = wid & 3;
  const int m0 = blockIdx.x * 128;
  const int b = m0 >> 12;
  const int h0 = (m0 & 4095) >> 6;
  const int tg = blockIdx.y;
  const int ts0 = tg ? 4 : 0;
  const int ntap = tg ? 5 : 4;
  const int r_s = tid >> 2, sub = tid & 3;
  const int nB = tid & 255, hB = tid >> 8;
  const int h_rs = h0 + (r_s >> 6), w_rs = r_s & 63;
  const s16x8* Ap = (const s16x8*)A_lds;
  const s16x8* Bp = (const s16x8*)B_lds;
  const u16* wrowB = wt + (size_t)nB*2304 + hB*32;
  f32x4 acc[4][4];
#pragma unroll
  for(int mf=0;mf<4;mf++)
#pragma unroll
    for(int nf=0;nf<4;nf++) acc[mf][nf] = f32x4_zero();

  auto loadA = [&](int p, s16x8& a0, s16x8& a1){
    const int tp = ts0 + (p >> 2);
    const int c0 = (p & 3)*64 + sub*8;
    const int ty = tp/3, tx = tp - ty*3;
    const int y = h_rs - 1 + ty, x = w_rs - 1 + tx;
    const bool vld = (y>=0) & (y<64) & (x>=0) & (x<64);
    a0 = s16x8_zero(); a1 = s16x8_zero();
    if(vld){
      const u16* src = a_in + (((size_t)((b<<12) + (y<<6) + x)) << 8) + c0;
      a0 = *(const s16x8*)(src);
      a1 = *(const s16x8*)(src + 32);
    }
  };
  auto loadB = [&](int p, s16x8& b0, s16x8& b1, s16x8& b2, s16x8& b3){
    const u16* src = wrowB + (ts0 + (p >> 2))*256 + (p & 3)*64;
    b0 = *(const s16x8*)(src);
    b1 = *(const s16x8*)(src + 8);
    b2 = *(const s16x8*)(src + 16);
    b3 = *(const s16x8*)(src + 24);
  };
  auto mfma_phase = [&](){
#pragma unroll
    for(int kk=0;kk<2;kk++){
      s16x8 af[4], bf[4];
#pragma unroll
      for(int mf=0;mf<4;mf++) af[mf] = Ap[(kk*4+quad)*128 + wm*64 + mf*16 + ln];
#pragma unroll
      for(int nf=0;nf<4;nf++) bf[nf] = Bp[(kk*4+quad)*256 + wn*64 + nf*16 + ln];
#pragma unroll
      for(int mf=0;mf<4;mf++)
#pragma unroll
        for(int nf=0;nf<4;nf++) acc[mf][nf] = mfma16(af[mf], bf[nf], acc[mf][nf]);
    }
  };

  const int NP = ntap * 4;   // 16 or 20 (even)
  s16x8 xA0,xA1, xB0,xB1,xB2,xB3;
  s16x8 yA0,yA1, yB0,yB1,yB2,yB3;
  loadA(0, xA0,xA1); loadB(0, xB0,xB1,xB2,xB3);
  loadA(1, yA0,yA1); loadB(1, yB0,yB1,yB2,yB3);

  for(int p = 0; p < NP; p += 2){
    // ---- phase p (set X)
    bar_lds();
    *(s16x8*)(&A_lds[sub][r_s][0])   = xA0;
    *(s16x8*)(&A_lds[4+sub][r_s][0]) = xA1;
    *(s16x8*)(&B_lds[hB*4+0][nB][0]) = xB0;
    *(s16x8*)(&B_lds[hB*4+1][nB][0]) = xB1;
    *(s16x8*)(&B_lds[hB*4+2][nB][0]) = xB2;
    *(s16x8*)(&B_lds[hB*4+3][nB][0]) = xB3;
    if(p + 2 < NP){ loadA(p + 2, xA0,xA1); loadB(p + 2, xB0,xB1,xB2,xB3); }
    bar_lds();
    mfma_phase();
    // ---- phase p+1 (set Y)
    bar_lds();
    *(s16x8*)(&A_lds[sub][r_s][0])   = yA0;
    *(s16x8*)(&A_lds[4+sub][r_s][0]) = yA1;
    *(s16x8*)(&B_lds[hB*4+0][nB][0]) = yB0;
    *(s16x8*)(&B_lds[hB*4+1][nB][0]) = yB1;
    *(s16x8*)(&B_lds[hB*4+2][nB][0]) = yB2;
    *(s16x8*)(&B_lds[hB*4+3][nB][0]) = yB3;
    if(p + 3 < NP){ loadA(p + 3, yA0,yA1); loadB(p + 3, yB0,yB1,yB2,yB3); }
    bar_lds();
    mfma_phase();
  }
#pragma unroll
  for(int mf=0;mf<4;mf++)
#pragma unroll
    for(int nf=0;nf<4;nf++){
      const int col = wn*64 + nf*16 + ln;
#pragma unroll
      for(int i=0;i<4;i++){
        const int row = wm*64 + mf*16 + quad*4 + i;
        unsafeAtomicAdd(outa + (size_t)(m0+row)*256 + col, acc[mf][nf][i]);
      }
    }
}

// ---------------- BN stats: per-channel sum/sumsq over M=16384 ----------------
__global__ void k_stats(const float* __restrict__ acc, float* __restrict__ sum,
                        float* __restrict__ sq){
  const int m0 = blockIdx.x*64;
  const int c = threadIdx.x;
  float s = 0.f, q = 0.f;
  for(int i=0;i<64;i++){
    float v = acc[(size_t)(m0+i)*256 + c];
    s += v; q += v*v;
  }
  unsafeAtomicAdd(sum + c, s);
  unsafeAtomicAdd(sq + c, q);
}

// ---------------- BN1 + ReLU -> bf16 NHWC ----------------
__global__ void k_bn1(const float* __restrict__ acc, const float* __restrict__ sum,
                      const float* __restrict__ sq, const float* __restrict__ g,
                      const float* __restrict__ bt, u16* __restrict__ o){
  __shared__ float sc[256], sh[256];
  const int t = threadIdx.x;
  {
    float mean = sum[t] * (1.f/16384.f);
    float var  = sq[t] * (1.f/16384.f) - mean*mean;
    float rstd = rsqrtf(var + 1e-5f);
    float s = g[t] * rstd;
    sc[t] = s; sh[t] = bt[t] - mean*s;
  }
  __syncthreads();
  const int c4 = (t & 63) * 4;
  const float s0 = sc[c4], s1 = sc[c4+1], s2 = sc[c4+2], s3 = sc[c4+3];
  const float h0 = sh[c4], h1 = sh[c4+1], h2 = sh[c4+2], h3 = sh[c4+3];
#pragma unroll
  for(int k=0;k<4;k++){
    int m = blockIdx.x*16 + k*4 + (t>>6);
    const float4 v = *(const float4*)(acc + (size_t)m*256 + c4);
    unsigned int lo = (unsigned int)(u16)f2bf(fmaxf(0.f, v.x*s0 + h0))
                    | ((unsigned int)(u16)f2bf(fmaxf(0.f, v.y*s1 + h1)) << 16);
    unsigned int hi = (unsigned int)(u16)f2bf(fmaxf(0.f, v.z*s2 + h2))
                    | ((unsigned int)(u16)f2bf(fmaxf(0.f, v.w*s3 + h3)) << 16);
    uint2 pr; pr.x = lo; pr.y = hi;
    *(uint2*)(o + (size_t)m*256 + c4) = pr;
  }
}

// ---------------- BN2 + ReLU + NHWC->NCHW fp32 output ----------------
__global__ void k_bn2_out(const float* __restrict__ acc, const float* __restrict__ sum,
                          const float* __restrict__ sq, const float* __restrict__ g,
                          const float* __restrict__ bt, float* __restrict__ out){
  __shared__ float tile[64][65];
  __shared__ float sc[64], sh[64];
  const int t = threadIdx.x;
  const int b = blockIdx.z, c0 = blockIdx.y*64, hw0 = blockIdx.x*64;
  if(t < 64){
    int c = c0 + t;
    float mean = sum[c] * (1.f/16384.f);
    float var  = sq[c] * (1.f/16384.f) - mean*mean;
    float rstd = rsqrtf(var + 1e-5f);
    float s = g[c] * rstd;
    sc[t] = s; sh[t] = bt[c] - mean*s;
  }
  __syncthreads();
#pragma unroll
  for(int k=0;k<16;k++){
    int idx = t + k*256;
    int wl = idx >> 6, cl = idx & 63;
    float v = acc[(size_t)((b<<12) + hw0 + wl)*256 + c0 + cl];
    tile[wl][cl] = fmaxf(0.f, v*sc[cl] + sh[cl]);
  }
  __syncthreads();
#pragma unroll
  for(int k=0;k<16;k++){
    int idx = t + k*256;
    int cl = idx >> 6, wl = idx & 63;
    out[(size_t)(b*256 + c0 + cl)*4096 + hw0 + wl] = tile[wl][cl];
  }
}

extern "C" void kernel_launch(void* const* d_in, const int* in_sizes, int n_in,
                              void* d_out, int out_size, void* d_ws, size_t ws_size,
                              hipStream_t stream){
  const float* in_v  = (const float*)d_in[0];
  const float* in_i  = (const float*)d_in[1];
  const float* w_off = (const float*)d_in[2];
  const float* b_off = (const float*)d_in[3];
  const float* w_dcn = (const float*)d_in[4];
  const float* g1    = (const float*)d_in[5];
  const float* bt1   = (const float*)d_in[6];
  const float* w2    = (const float*)d_in[7];
  const float* g2    = (const float*)d_in[8];
  const float* bt2   = (const float*)d_in[9];
  float* out = (float*)d_out;
  char* ws = (char*)d_ws;

  float* off_acc  = (float*)(ws + OFF_ACC_B);
  float* out1_acc = (float*)(ws + OUT1_ACC_B);
  float* out2_acc = (float*)(ws + OUT2_ACC_B);
  float* stats    = (float*)(ws + STATS_B);
  float* sum1 = stats,       *sq1 = stats + 256;
  float* sum2 = stats + 512, *sq2 = stats + 768;
  u16* xn    = (u16*)(ws + XN_B);
  u16* out1n = (u16*)(ws + OUT1N_B);
  u16* wofft = (u16*)(ws + WOFFT_B);
  u16* wdcnt = (u16*)(ws + WDCNT_B);
  u16* w2t   = (u16*)(ws + W2T_B);

  hipMemsetAsync(ws, 0, ZERO_BYTES, stream);
  k_x_to_nhwc<<<dim3(64,8,4), 256, 0, stream>>>(in_v, in_i, xn);
  k_prep_woff<<<576, 256, 0, stream>>>(w_off, wofft);
  k_prep_wdcn<<<4608, 256, 0, stream>>>(w_dcn, wdcnt);
  k_prep_w2<<<2304, 256, 0, stream>>>(w2, w2t);
  k_conv_off<<<dim3(128,4), 256, 0, stream>>>(xn, wofft, off_acc);
  k_dcn<<<dim3(128,2), 512, 0, stream>>>(xn, wdcnt, off_acc, b_off, out1_acc);
  k_stats<<<256, 256, 0, stream>>>(out1_acc, sum1, sq1);
  k_bn1<<<1024, 256, 0, stream>>>(out1_acc, sum1, sq1, g1, bt1, out1n);
  k_conv2<<<dim3(128,2), 512, 0, stream>>>(out1n, w2t, out2_acc);
  k_stats<<<256, 256, 0, stream>>>(out2_acc, sum2, sq2);
  k_bn2_out<<<dim3(64,4,4), 256, 0, stream>>>(out2_acc, sum2, sq2, g2, bt2, out);
}